// Round 8
// baseline (528.963 us; speedup 1.0000x reference)
//
#include <hip/hip_runtime.h>
#include <hip/hip_bf16.h>

// Problem constants
#define Bb   4
#define Nn   2048
#define Dd   1024
#define Hh   16
#define HDd  64
#define IN3  3072          // 3 * H * HD
#define RR   8192          // B * N

typedef __attribute__((ext_vector_type(8))) short short8;
typedef __attribute__((ext_vector_type(4))) float floatx4;

#define MFMA16(a, b, c) __builtin_amdgcn_mfma_f32_16x16x32_bf16((a), (b), (c), 0, 0, 0)

static __device__ __forceinline__ unsigned short f2bf(float f) {
    union { float f; unsigned int u; } v; v.f = f;
    unsigned int r = v.u + 0x7fffu + ((v.u >> 16) & 1u);   // RNE
    return (unsigned short)(r >> 16);
}
static __device__ __forceinline__ float bf2f(unsigned short h) {
    union { unsigned int u; float f; } v; v.u = ((unsigned int)h) << 16;
    return v.f;
}

// raw v_exp_f32 (args small; no OCML fixup needed) [R6 win]
static __device__ __forceinline__ float fast_exp2(float x) {
#if __has_builtin(__builtin_amdgcn_exp2f)
    return __builtin_amdgcn_exp2f(x);
#else
    return exp2f(x);
#endif
}

// sin/cos via v_fract + v_sin/v_cos (revolutions) [R10 win, fused rope]
static __device__ __forceinline__ void sincos_rev(float ang, float& s, float& c) {
#if __has_builtin(__builtin_amdgcn_sinf) && __has_builtin(__builtin_amdgcn_cosf)
    float rev = ang * 0.15915494309189535f;
    rev = rev - floorf(rev);
    s = __builtin_amdgcn_sinf(rev);
    c = __builtin_amdgcn_cosf(rev);
#else
    s = sinf(ang);
    c = cosf(ang);
#endif
}

// async global->LDS DMA, 16B/lane (validated in-session R5-R10)
typedef const __attribute__((address_space(1))) void* gas1_t;
typedef __attribute__((address_space(3))) void* las3_t;
static __device__ __forceinline__ void load_lds16(const void* g, void* l) {
    __builtin_amdgcn_global_load_lds((gas1_t)(unsigned long long)g,
                                     (las3_t)(unsigned int)(unsigned long long)l,
                                     16, 0, 0);
}

// ---------------------------------------------------------------------------
// K0: transpose fp32 [rows][cols] -> bf16 [cols][rows]  (weights to B^T form)
// ---------------------------------------------------------------------------
__global__ void transpose_w(const float* __restrict__ src, unsigned short* __restrict__ dst,
                            int rows, int cols) {
    __shared__ float tile[32][33];
    int c0 = blockIdx.x * 32, r0 = blockIdx.y * 32;
    int tx = threadIdx.x, ty = threadIdx.y;   // 32 x 8
#pragma unroll
    for (int i = 0; i < 4; ++i) tile[ty + 8 * i][tx] = src[(r0 + ty + 8 * i) * cols + c0 + tx];
    __syncthreads();
#pragma unroll
    for (int i = 0; i < 4; ++i) dst[(c0 + ty + 8 * i) * rows + r0 + tx] = f2bf(tile[tx][ty + 8 * i]);
}

// ---------------------------------------------------------------------------
// K1: LayerNorm fp32 -> bf16, one block (256 thr) per row of 1024
// ---------------------------------------------------------------------------
__global__ __launch_bounds__(256) void ln_kernel(const float* __restrict__ x,
                                                 const float* __restrict__ g,
                                                 const float* __restrict__ be,
                                                 unsigned short* __restrict__ xn) {
    int row = blockIdx.x, t = threadIdx.x;
    float4 v = ((const float4*)(x + row * Dd))[t];
    float s  = v.x + v.y + v.z + v.w;
    float sq = v.x * v.x + v.y * v.y + v.z * v.z + v.w * v.w;
#pragma unroll
    for (int off = 1; off < 64; off <<= 1) { s += __shfl_xor(s, off); sq += __shfl_xor(sq, off); }
    __shared__ float ps[4], pq2[4];
    int wv = t >> 6;
    if ((t & 63) == 0) { ps[wv] = s; pq2[wv] = sq; }
    __syncthreads();
    s  = ps[0] + ps[1] + ps[2] + ps[3];
    sq = pq2[0] + pq2[1] + pq2[2] + pq2[3];
    float mu   = s * (1.0f / Dd);
    float var  = sq * (1.0f / Dd) - mu * mu;
    float rstd = rsqrtf(var + 1e-5f);
    float4 gg = ((const float4*)g)[t];
    float4 bb = ((const float4*)be)[t];
    ushort4 o;
    o.x = f2bf((v.x - mu) * rstd * gg.x + bb.x);
    o.y = f2bf((v.y - mu) * rstd * gg.y + bb.y);
    o.z = f2bf((v.z - mu) * rstd * gg.z + bb.z);
    o.w = f2bf((v.w - mu) * rstd * gg.w + bb.w);
    ((ushort4*)(xn + row * Dd))[t] = o;
}

// ---------------------------------------------------------------------------
// K2: qkv GEMM v3 — 128x256 tile, 2-phase/K-tile counted-vmcnt schedule.
// [R7: left the top-5 (<74us, was 75.5). Keep unchanged.]
// ---------------------------------------------------------------------------
__global__ __launch_bounds__(512, 1) void gemm_qkv(const unsigned short* __restrict__ A,
                                                   const unsigned short* __restrict__ Bt,
                                                   unsigned short* __restrict__ qo,
                                                   unsigned short* __restrict__ ko,
                                                   unsigned short* __restrict__ vo) {
    __shared__ unsigned short LDS[49152];   // 96 KiB: A[2][8192] @0, B[2][16384] @16384
    int r0 = blockIdx.x * 128, c0 = blockIdx.y * 256;
    int tid = threadIdx.x;
    int wv = tid >> 6, lane = tid & 63, l15 = lane & 15, quad = lane >> 4;
    int wm = wv >> 2, wn = wv & 3;          // 2M x 4N wave grid (64x64 each)

    floatx4 acc[4][4] = {};
    int swz0 = (quad ^ (l15 & 7)) << 3;            // k-chunk quad   (ks=0)
    int swz1 = ((4 | quad) ^ (l15 & 7)) << 3;      // k-chunk 4+quad (ks=1)

    auto stageA = [&](int tt) {                    // 16 KB: 2 loads/lane
        unsigned short* base = &LDS[(tt & 1) * 8192];
        int k0 = tt * 64;
#pragma unroll
        for (int i = 0; i < 2; ++i) {
            int qq = (wv * 2 + i) * 64 + lane;     // 0..1023 (16B units)
            int row = qq >> 3, cp = qq & 7;
            int sc = cp ^ (row & 7);
            load_lds16(&A[(r0 + row) * 1024 + k0 + sc * 8], &base[qq * 8]);
        }
    };
    auto stageB = [&](int tt) {                    // 32 KB: 4 loads/lane
        unsigned short* base = &LDS[16384 + (tt & 1) * 16384];
        int k0 = tt * 64;
#pragma unroll
        for (int i = 0; i < 4; ++i) {
            int qq = (wv * 4 + i) * 64 + lane;     // 0..2047 (16B units)
            int row = qq >> 3, cp = qq & 7;
            int sc = cp ^ (row & 7);
            load_lds16(&Bt[(c0 + row) * 1024 + k0 + sc * 8], &base[qq * 8]);
        }
    };

    // prologue: A(0) 2 + B(0) 4 + A(1) 2 loads; vmcnt(2) -> tile0 landed
    stageA(0); stageB(0); stageA(1);
    asm volatile("s_waitcnt vmcnt(2)" ::: "memory");
    __builtin_amdgcn_s_barrier();

    for (int t = 0; t < 16; ++t) {
        int abuf = (t & 1) * 8192;
        int bbuf = 16384 + (t & 1) * 16384;
        short8 af[4][2], bf[2][2];

        // ---- phase 0: wave cols 0..31 (ni 0,1) ----
        if (t < 15) stageB(t + 1);
#pragma unroll
        for (int mi = 0; mi < 4; ++mi) {
            af[mi][0] = *(const short8*)&LDS[abuf + (wm * 64 + mi * 16 + l15) * 64 + swz0];
            af[mi][1] = *(const short8*)&LDS[abuf + (wm * 64 + mi * 16 + l15) * 64 + swz1];
        }
#pragma unroll
        for (int ni = 0; ni < 2; ++ni) {
            bf[ni][0] = *(const short8*)&LDS[bbuf + (wn * 64 + ni * 16 + l15) * 64 + swz0];
            bf[ni][1] = *(const short8*)&LDS[bbuf + (wn * 64 + ni * 16 + l15) * 64 + swz1];
        }
        __builtin_amdgcn_s_barrier();
        asm volatile("s_waitcnt lgkmcnt(0)" ::: "memory");
        __builtin_amdgcn_s_setprio(1);
#pragma unroll
        for (int ks = 0; ks < 2; ++ks)
#pragma unroll
            for (int mi = 0; mi < 4; ++mi)
#pragma unroll
                for (int ni = 0; ni < 2; ++ni)
                    acc[mi][ni] = MFMA16(af[mi][ks], bf[ni][ks], acc[mi][ni]);
        __builtin_amdgcn_s_setprio(0);
        __builtin_amdgcn_s_barrier();

        // ---- phase 1: wave cols 32..63 (ni 2,3); af held in regs ----
        if (t < 14) stageA(t + 2);   // lands in CURRENT A-buf; A-reads done at ph0 barrier
#pragma unroll
        for (int ni = 0; ni < 2; ++ni) {
            bf[ni][0] = *(const short8*)&LDS[bbuf + (wn * 64 + 32 + ni * 16 + l15) * 64 + swz0];
            bf[ni][1] = *(const short8*)&LDS[bbuf + (wn * 64 + 32 + ni * 16 + l15) * 64 + swz1];
        }
        __builtin_amdgcn_s_barrier();
        asm volatile("s_waitcnt lgkmcnt(0)" ::: "memory");
        __builtin_amdgcn_s_setprio(1);
#pragma unroll
        for (int ks = 0; ks < 2; ++ks)
#pragma unroll
            for (int mi = 0; mi < 4; ++mi)
#pragma unroll
                for (int ni = 0; ni < 2; ++ni)
                    acc[mi][2 + ni] = MFMA16(af[mi][ks], bf[ni][ks], acc[mi][2 + ni]);
        __builtin_amdgcn_s_setprio(0);
        // counted vmcnt: retire A(t+1)+B(t+1) (needed by body t+1); leave
        // A(t+2) (2 loads) in flight across the barrier (T4).
        if (t < 14)       asm volatile("s_waitcnt vmcnt(2)" ::: "memory");
        else if (t == 14) asm volatile("s_waitcnt vmcnt(0)" ::: "memory");   // drain tail
        __builtin_amdgcn_s_barrier();
    }

    // ---- fused RoPE for q,k blocks (block-uniform branch) ----
    if (c0 < 2048) {
        const float crope = 13.287712379549449f / 32.0f;   // log2(10000)/32
        float invf0 = fast_exp2(-(float)l15 * crope);          // j = l15
        float invf1 = fast_exp2(-(float)(l15 + 16) * crope);   // j = 16+l15
#pragma unroll
        for (int mi = 0; mi < 4; ++mi)
#pragma unroll
            for (int r2 = 0; r2 < 4; ++r2) {
                int rr = r0 + wm * 64 + mi * 16 + quad * 4 + r2;
                float n = (float)(rr & 2047);
                float s0, c0r, s1, c1r;
                sincos_rev(n * invf0, s0, c0r);
                sincos_rev(n * invf1, s1, c1r);
                float t1a = acc[mi][0][r2], t2a = acc[mi][2][r2];
                acc[mi][0][r2] = t1a * c0r - t2a * s0;
                acc[mi][2][r2] = t2a * c0r + t1a * s0;
                float t1b = acc[mi][1][r2], t2b = acc[mi][3][r2];
                acc[mi][1][r2] = t1b * c1r - t2b * s1;
                acc[mi][3][r2] = t2b * c1r + t1b * s1;
            }
    }
    // q pre-scale: fold softmax scale*log2(e) into q so attn does raw exp2
    if (c0 < 1024) {
        const float qsc = 0.125f * 1.4426950408889634f;
#pragma unroll
        for (int mi = 0; mi < 4; ++mi)
#pragma unroll
            for (int ni = 0; ni < 4; ++ni)
#pragma unroll
                for (int r2 = 0; r2 < 4; ++r2) acc[mi][ni][r2] *= qsc;
    }
    // epilogue: C/D layout col = lane&15, row = quad*4 + reg (verified m89/m91)
    unsigned short* outp = (c0 < 1024) ? qo : (c0 < 2048) ? ko : vo;  // block-uniform
#pragma unroll
    for (int ni = 0; ni < 4; ++ni) {
        int c = c0 + wn * 64 + ni * 16 + l15;
        int cin = c & 1023;
        int h = cin >> 6, j = cin & 63;
#pragma unroll
        for (int mi = 0; mi < 4; ++mi) {
#pragma unroll
            for (int r2 = 0; r2 < 4; ++r2) {
                int rr = r0 + wm * 64 + mi * 16 + quad * 4 + r2;
                int b = rr >> 11, n = rr & 2047;
                int bh = b * 16 + h;
                outp[(bh * 2048 + n) * 64 + j] = f2bf(acc[mi][ni][r2]);
            }
        }
    }
}

// ---------------------------------------------------------------------------
// K2b: v [bh][n][hd] -> vt [bh][hd][n], key columns PERMUTED within each
// 32-key block: position p = 8q+4h+r holds key 16h+4q+r (matches the K=32
// PV A-fragment k-order in attn_kernel). [R8/R9: numerically verified]
// ---------------------------------------------------------------------------
__global__ __launch_bounds__(256) void vtrans(const unsigned short* __restrict__ v,
                                              unsigned short* __restrict__ vt) {
    __shared__ unsigned short T[64][72];
    int bh = blockIdx.y, n0 = blockIdx.x * 64;
    int t = threadIdx.x;
    int nl = t >> 2, c = (t & 3) * 16;
    const unsigned short* src = v + ((bh * 2048) + n0 + nl) * 64 + c;
    *(short8*)&T[nl][c]     = *(const short8*)src;
    *(short8*)&T[nl][c + 8] = *(const short8*)(src + 8);
    __syncthreads();
    int hd = t >> 2, nc = (t & 3) * 16;
    unsigned short tmp[16];
#pragma unroll
    for (int i = 0; i < 16; ++i) {
        int pos = nc + i;
        int blk = pos >> 5, p = pos & 31;
        int kq = (p >> 3) & 3, hh = (p >> 2) & 1, r = p & 3;
        tmp[i] = T[blk * 32 + hh * 16 + kq * 4 + r][hd];
    }
    unsigned short* dst = vt + ((bh * 64) + hd) * 2048 + n0 + nc;
    *(short8*)dst       = *(const short8*)&tmp[0];
    *(short8*)(dst + 8) = *(const short8*)&tmp[8];
}

// ---------------------------------------------------------------------------
// K4: flash attention v14 — perfect packing. R7: 74.2us, MfmaUtil 43.8 +
// VALUBusy 42.6 = 87% combined, Occupancy 23%. Two structural losses:
// (a) LDS 48K -> only 3 blocks/CU but grid 1024 = 4 blocks/CU -> 3+1 tail
//     (+25%); (b) 1.9 waves/SIMD limits MFMA/VALU cross-wave overlap.
// v14: 2-deep KV rotation (LDS 32K) -> 4 blocks/CU EXACTLY (zero tail),
// 16 waves/CU (4/SIMD). Cost: vmcnt(0) per body — cheap: K/V is L2-resident
// (XCD-affine, R3: HBM 4-8%) and the stage is issued ~600cyc before the
// drain. launch_bounds(256,4): cap 128 >= 84 measured VGPR, no spill.
// ---------------------------------------------------------------------------
__global__ __launch_bounds__(256, 4) void attn_kernel(const unsigned short* __restrict__ q,
                                                      const unsigned short* __restrict__ k,
                                                      const unsigned short* __restrict__ vt,
                                                      unsigned short* __restrict__ attn) {
    __shared__ unsigned short KVs[2][2][64 * 64];  // [buf][K/V][row*64+swizzled] 32 KiB
    // XCD-affine decode: fid%8 = XCD (dispatch round-robin); each XCD owns
    // bh = {c, c+8, ..., c+56} and walks qi fastest -> K/V L2-resident. [R3 ✓]
    int fid = blockIdx.x;
    int xcd = fid & 7, rest = fid >> 3;
    int qi = rest & 15, bhg = rest >> 4;
    int bh = bhg * 8 + xcd;
    int q0 = qi * 128;
    int tid = threadIdx.x;
    int wave = tid >> 6, lane = tid & 63, l15 = lane & 15, quad = lane >> 4;
    const unsigned short* qb  = q  + bh * (Nn * HDd);
    const unsigned short* kbp = k  + bh * (Nn * HDd);
    const unsigned short* vb  = vt + bh * (HDd * Nn);   // [hd][n], key-permuted
    int qbase = q0 + wave * 32;

    // Q fragments (B-operand of 16x16x32), 2 groups of 16 q-rows per wave
    short8 bq[2][2];
#pragma unroll
    for (int g = 0; g < 2; ++g) {
        bq[g][0] = *(const short8*)&qb[(qbase + g * 16 + l15) * 64 + quad * 8];
        bq[g][1] = *(const short8*)&qb[(qbase + g * 16 + l15) * 64 + 32 + quad * 8];
    }

    // 4 waves stage 16 KB (K 8 KB + V 8 KB): 2 K + 2 V loads per lane
    auto stage = [&](int buf, int kb0) {
#pragma unroll
        for (int i = 0; i < 2; ++i) {
            int c = wave * 2 + i;
            int p = c * 64 + lane;
            int row = p >> 3, pr = p & 7;
            int sc = pr ^ (row & 7);                       // XOR chunk swizzle
            load_lds16(&kbp[(kb0 + row) * 64 + sc * 8], &KVs[buf][0][p * 8]);
            load_lds16(&vb[row * Nn + kb0 + sc * 8],    &KVs[buf][1][p * 8]);
        }
    };

    floatx4 ot[2][4] = {};                 // [g][ht]: O[q=quad*4+r][hd=ht*16+l15]
    floatx4 osum[2] = {};                  // row-sum of P via ones-MFMA; same row map
    const floatx4 fz = {0.0f, 0.0f, 0.0f, 0.0f};
    const short8 vones = {(short)0x3F80, (short)0x3F80, (short)0x3F80, (short)0x3F80,
                          (short)0x3F80, (short)0x3F80, (short)0x3F80, (short)0x3F80};
    int swz0 = (quad ^ (l15 & 7)) << 3;                    // chunk quad   (c=0)
    int swz1 = ((4 | quad) ^ (l15 & 7)) << 3;              // chunk 4+quad (c=1)

    // body(cur, kt): compute tile kt from KVs[cur]; stage kt+1 into cur^1
    // (buffer last read at body kt-1 — its end barrier separates).
    auto body = [&](int cur, int kt) {
        if (kt < 31) stage(cur ^ 1, (kt + 1) * 64);
        const unsigned short* Kc = KVs[cur][0];
        const unsigned short* Vc = KVs[cur][1];
        // ---- S^T = K.Q^T ----
        short8 ka0[4], ka1[4];
#pragma unroll
        for (int mb = 0; mb < 4; ++mb) {
            ka0[mb] = *(const short8*)&Kc[(mb * 16 + l15) * 64 + swz0];
            ka1[mb] = *(const short8*)&Kc[(mb * 16 + l15) * 64 + swz1];
        }
        short8 bv0[4], bv1[4];
#pragma unroll
        for (int ht = 0; ht < 4; ++ht) {
            int row = (ht * 16 + l15) * 64;
            bv0[ht] = *(const short8*)&Vc[row + swz0];
            bv1[ht] = *(const short8*)&Vc[row + swz1];
        }
#pragma unroll
        for (int g = 0; g < 2; ++g) {
            floatx4 st[4];
            __builtin_amdgcn_s_setprio(1);
#pragma unroll
            for (int mb = 0; mb < 4; ++mb) {
                floatx4 z = MFMA16(ka0[mb], bq[g][0], fz);
                st[mb] = MFMA16(ka1[mb], bq[g][1], z);
            }
            __builtin_amdgcn_s_setprio(0);
            // ---- P = exp2(S) (q pre-scaled); pack K=32 A-fragments ----
            short8 pa[2];
#pragma unroll
            for (int c = 0; c < 2; ++c) {
                union { ushort4 u[2]; short8 s; } w;
#pragma unroll
                for (int t2 = 0; t2 < 2; ++t2) {
                    int mb = 2 * c + t2;
                    float p0 = fast_exp2(st[mb][0]);
                    float p1 = fast_exp2(st[mb][1]);
                    float p2 = fast_exp2(st[mb][2]);
                    float p3 = fast_exp2(st[mb][3]);
                    *(__hip_bfloat162*)&w.u[t2].x = __float22bfloat162_rn(float2{p0, p1});
                    *(__hip_bfloat162*)&w.u[t2].z = __float22bfloat162_rn(float2{p2, p3});
                }
                pa[c] = w.s;
            }
            // ---- O[q][hd] += P.V ; denom += P.1  (all in matrix pipe) ----
            __builtin_amdgcn_s_setprio(1);
            osum[g] = MFMA16(pa[0], vones, osum[g]);
            osum[g] = MFMA16(pa[1], vones, osum[g]);
#pragma unroll
            for (int ht = 0; ht < 4; ++ht) {
                ot[g][ht] = MFMA16(pa[0], bv0[ht], ot[g][ht]);
                ot[g][ht] = MFMA16(pa[1], bv1[ht], ot[g][ht]);
            }
            __builtin_amdgcn_s_setprio(0);
        }
        // drain this body's stage (issued ~600cyc ago, L2-resident) so the
        // block can read buf cur^1 next body; barrier promotes block-wide.
        if (kt < 31) asm volatile("s_waitcnt vmcnt(0)" ::: "memory");
        __builtin_amdgcn_s_barrier();
    };

    stage(0, 0);
    asm volatile("s_waitcnt vmcnt(0)" ::: "memory");   // tile 0 landed
    __builtin_amdgcn_s_barrier();
    for (int kt = 0; kt < 32; kt += 2) {
        body(0, kt);
        body(1, kt + 1);
    }

    // ---- epilogue: invl directly from osum (same row map as ot) ----
    int b = bh >> 4, h = bh & 15;
    unsigned short* ob = ((unsigned short*)KVs) + wave * 1152;   // 16 rows x 72
#pragma unroll
    for (int g = 0; g < 2; ++g) {
        float il[4];
#pragma unroll
        for (int r = 0; r < 4; ++r) il[r] = 1.0f / osum[g][r];
#pragma unroll
        for (int ht = 0; ht < 4; ++ht)
#pragma unroll
            for (int r = 0; r < 4; ++r)
                ob[(quad * 4 + r) * 72 + ht * 16 + l15] = f2bf(ot[g][ht][r] * il[r]);
        // wave-private region: ds_write -> ds_read ordered by lgkmcnt within wave
        int q_loc = lane >> 2, seg = lane & 3;
        unsigned short* dst = attn + ((long)(b * Nn + q0 + wave * 32 + g * 16 + q_loc)) * 1024 + h * 64 + seg * 16;
        *(short8*)dst       = *(const short8*)&ob[q_loc * 72 + seg * 16];
        *(short8*)(dst + 8) = *(const short8*)&ob[q_loc * 72 + seg * 16 + 8];
    }
}

// ---------------------------------------------------------------------------
// K5: out-projection v2 — retiled to the proven gemm_qkv v3 structure
// (128x256 tile, 2-phase/K-tile, counted vmcnt). Grid 64x4 = 256 blocks =
// EXACTLY 1 round at 1 block/CU (was: 512-block m97-structure, 2 rounds).
// Epilogue: bias + fp32 store (no RoPE/q-scale).
// ---------------------------------------------------------------------------
__global__ __launch_bounds__(512, 1) void gemm_out(const unsigned short* __restrict__ A,
                                                   const unsigned short* __restrict__ Bt,
                                                   const float* __restrict__ bout,
                                                   float* __restrict__ out) {
    __shared__ unsigned short LDS[49152];   // 96 KiB: A[2][8192] @0, B[2][16384] @16384
    int r0 = blockIdx.x * 128, c0 = blockIdx.y * 256;
    int tid = threadIdx.x;
    int wv = tid >> 6, lane = tid & 63, l15 = lane & 15, quad = lane >> 4;
    int wm = wv >> 2, wn = wv & 3;          // 2M x 4N wave grid (64x64 each)

    floatx4 acc[4][4] = {};
    int swz0 = (quad ^ (l15 & 7)) << 3;
    int swz1 = ((4 | quad) ^ (l15 & 7)) << 3;

    auto stageA = [&](int tt) {
        unsigned short* base = &LDS[(tt & 1) * 8192];
        int k0 = tt * 64;
#pragma unroll
        for (int i = 0; i < 2; ++i) {
            int qq = (wv * 2 + i) * 64 + lane;
            int row = qq >> 3, cp = qq & 7;
            int sc = cp ^ (row & 7);
            load_lds16(&A[(r0 + row) * 1024 + k0 + sc * 8], &base[qq * 8]);
        }
    };
    auto stageB = [&](int tt) {
        unsigned short* base = &LDS[16384 + (tt & 1) * 16384];
        int k0 = tt * 64;
#pragma unroll
        for (int i = 0; i < 4; ++i) {
            int qq = (wv * 4 + i) * 64 + lane;
            int row = qq >> 3, cp = qq & 7;
            int sc = cp ^ (row & 7);
            load_lds16(&Bt[(c0 + row) * 1024 + k0 + sc * 8], &base[qq * 8]);
        }
    };

    stageA(0); stageB(0); stageA(1);
    asm volatile("s_waitcnt vmcnt(2)" ::: "memory");
    __builtin_amdgcn_s_barrier();

    for (int t = 0; t < 16; ++t) {
        int abuf = (t & 1) * 8192;
        int bbuf = 16384 + (t & 1) * 16384;
        short8 af[4][2], bf[2][2];

        // ---- phase 0 ----
        if (t < 15) stageB(t + 1);
#pragma unroll
        for (int mi = 0; mi < 4; ++mi) {
            af[mi][0] = *(const short8*)&LDS[abuf + (wm * 64 + mi * 16 + l15) * 64 + swz0];
            af[mi][1] = *(const short8*)&LDS[abuf + (wm * 64 + mi * 16 + l15) * 64 + swz1];
        }
#pragma unroll
        for (int ni = 0; ni < 2; ++ni) {
            bf[ni][0] = *(const short8*)&LDS[bbuf + (wn * 64 + ni * 16 + l15) * 64 + swz0];
            bf[ni][1] = *(const short8*)&LDS[bbuf + (wn * 64 + ni * 16 + l15) * 64 + swz1];
        }
        __builtin_amdgcn_s_barrier();
        asm volatile("s_waitcnt lgkmcnt(0)" ::: "memory");
        __builtin_amdgcn_s_setprio(1);
#pragma unroll
        for (int ks = 0; ks < 2; ++ks)
#pragma unroll
            for (int mi = 0; mi < 4; ++mi)
#pragma unroll
                for (int ni = 0; ni < 2; ++ni)
                    acc[mi][ni] = MFMA16(af[mi][ks], bf[ni][ks], acc[mi][ni]);
        __builtin_amdgcn_s_setprio(0);
        __builtin_amdgcn_s_barrier();

        // ---- phase 1 ----
        if (t < 14) stageA(t + 2);
#pragma unroll
        for (int ni = 0; ni < 2; ++ni) {
            bf[ni][0] = *(const short8*)&LDS[bbuf + (wn * 64 + 32 + ni * 16 + l15) * 64 + swz0];
            bf[ni][1] = *(const short8*)&LDS[bbuf + (wn * 64 + 32 + ni * 16 + l15) * 64 + swz1];
        }
        __builtin_amdgcn_s_barrier();
        asm volatile("s_waitcnt lgkmcnt(0)" ::: "memory");
        __builtin_amdgcn_s_setprio(1);
#pragma unroll
        for (int ks = 0; ks < 2; ++ks)
#pragma unroll
            for (int mi = 0; mi < 4; ++mi)
#pragma unroll
                for (int ni = 0; ni < 2; ++ni)
                    acc[mi][2 + ni] = MFMA16(af[mi][ks], bf[ni][ks], acc[mi][2 + ni]);
        __builtin_amdgcn_s_setprio(0);
        if (t < 14)       asm volatile("s_waitcnt vmcnt(2)" ::: "memory");
        else if (t == 14) asm volatile("s_waitcnt vmcnt(0)" ::: "memory");
        __builtin_amdgcn_s_barrier();
    }

#pragma unroll
    for (int ni = 0; ni < 4; ++ni) {
        int c = c0 + wn * 64 + ni * 16 + l15;
        float bias = bout[c];
#pragma unroll
        for (int mi = 0; mi < 4; ++mi)
#pragma unroll
            for (int r2 = 0; r2 < 4; ++r2) {
                int rr = r0 + wm * 64 + mi * 16 + quad * 4 + r2;
                out[rr * 1024 + c] = acc[mi][ni][r2] + bias;
            }
    }
}

// ---------------------------------------------------------------------------
extern "C" void kernel_launch(void* const* d_in, const int* in_sizes, int n_in,
                              void* d_out, int out_size, void* d_ws, size_t ws_size,
                              hipStream_t stream) {
    const float* x    = (const float*)d_in[0];
    const float* g    = (const float*)d_in[1];
    const float* be   = (const float*)d_in[2];
    const float* wqkv = (const float*)d_in[3];
    const float* wout = (const float*)d_in[4];
    const float* bout = (const float*)d_in[5];
    float* out = (float*)d_out;

    char* ws = (char*)d_ws;
    unsigned short* xn    = (unsigned short*)(ws);                 // 16 MB
    unsigned short* wqkvT = (unsigned short*)(ws + 16777216);      //  6 MB
    unsigned short* woutT = (unsigned short*)(ws + 23068672);      //  2 MB
    unsigned short* qb    = (unsigned short*)(ws + 25165824);      // 16 MB
    unsigned short* kb    = (unsigned short*)(ws + 41943040);      // 16 MB
    unsigned short* vt    = (unsigned short*)(ws + 58720256);      // 16 MB
    unsigned short* attn  = (unsigned short*)(ws + 75497472);      // 16 MB
    unsigned short* vtmp  = attn;   // v row-layout parks in attn buffer

    transpose_w<<<dim3(IN3 / 32, Dd / 32), dim3(32, 8), 0, stream>>>(wqkv, wqkvT, Dd, IN3);
    transpose_w<<<dim3(Dd / 32, Dd / 32), dim3(32, 8), 0, stream>>>(wout, woutT, Dd, Dd);
    ln_kernel<<<RR, 256, 0, stream>>>(x, g, be, xn);
    gemm_qkv<<<dim3(RR / 128, IN3 / 256), 512, 0, stream>>>(xn, wqkvT, qb, kb, vtmp);
    vtrans<<<dim3(Nn / 64, Bb * Hh), 256, 0, stream>>>(vtmp, vt);
    attn_kernel<<<dim3(Nn / 128 * Bb * Hh), 256, 0, stream>>>(qb, kb, vt, attn);
    gemm_out<<<dim3(RR / 128, Dd / 256), 512, 0, stream>>>(attn, woutT, bout, out);
}

// Round 9
// 260.278 us; speedup vs baseline: 2.0323x; 2.0323x over previous
//
#include <hip/hip_runtime.h>
#include <hip/hip_bf16.h>

// Problem constants
#define Bb   4
#define Nn   2048
#define Dd   1024
#define Hh   16
#define HDd  64
#define IN3  3072          // 3 * H * HD
#define RR   8192          // B * N

// ---------------------------------------------------------------------------
// __launch_bounds__ EMPIRICAL MODEL (this compiler, gfx950) — R2/R5/R8 data:
//   VGPR cap = 512 / (2 * arg2) = 256 / arg2, INDEPENDENT of block size.
//   (512,1)->256  (512,2)->128  (256,2)->128  (256,3)->85  (256,4)->64
// Measured: (256,3) compiled to exactly 84; (256,4) and (512,4) -> 64 + huge
// scratch spill (WRITE_SIZE 1.05GB / 625MB). Compiler allocates UP TO cap.
// ---------------------------------------------------------------------------

typedef __attribute__((ext_vector_type(8))) short short8;
typedef __attribute__((ext_vector_type(4))) float floatx4;

#define MFMA16(a, b, c) __builtin_amdgcn_mfma_f32_16x16x32_bf16((a), (b), (c), 0, 0, 0)

static __device__ __forceinline__ unsigned short f2bf(float f) {
    union { float f; unsigned int u; } v; v.f = f;
    unsigned int r = v.u + 0x7fffu + ((v.u >> 16) & 1u);   // RNE
    return (unsigned short)(r >> 16);
}
static __device__ __forceinline__ float bf2f(unsigned short h) {
    union { unsigned int u; float f; } v; v.u = ((unsigned int)h) << 16;
    return v.f;
}

// raw v_exp_f32 (args small; no OCML fixup needed) [R6 win]
static __device__ __forceinline__ float fast_exp2(float x) {
#if __has_builtin(__builtin_amdgcn_exp2f)
    return __builtin_amdgcn_exp2f(x);
#else
    return exp2f(x);
#endif
}

// sin/cos via v_fract + v_sin/v_cos (revolutions) [R10 win, fused rope]
static __device__ __forceinline__ void sincos_rev(float ang, float& s, float& c) {
#if __has_builtin(__builtin_amdgcn_sinf) && __has_builtin(__builtin_amdgcn_cosf)
    float rev = ang * 0.15915494309189535f;
    rev = rev - floorf(rev);
    s = __builtin_amdgcn_sinf(rev);
    c = __builtin_amdgcn_cosf(rev);
#else
    s = sinf(ang);
    c = cosf(ang);
#endif
}

// async global->LDS DMA, 16B/lane (validated in-session R5-R10)
typedef const __attribute__((address_space(1))) void* gas1_t;
typedef __attribute__((address_space(3))) void* las3_t;
static __device__ __forceinline__ void load_lds16(const void* g, void* l) {
    __builtin_amdgcn_global_load_lds((gas1_t)(unsigned long long)g,
                                     (las3_t)(unsigned int)(unsigned long long)l,
                                     16, 0, 0);
}

// ---------------------------------------------------------------------------
// K0: transpose fp32 [rows][cols] -> bf16 [cols][rows]  (weights to B^T form)
// ---------------------------------------------------------------------------
__global__ void transpose_w(const float* __restrict__ src, unsigned short* __restrict__ dst,
                            int rows, int cols) {
    __shared__ float tile[32][33];
    int c0 = blockIdx.x * 32, r0 = blockIdx.y * 32;
    int tx = threadIdx.x, ty = threadIdx.y;   // 32 x 8
#pragma unroll
    for (int i = 0; i < 4; ++i) tile[ty + 8 * i][tx] = src[(r0 + ty + 8 * i) * cols + c0 + tx];
    __syncthreads();
#pragma unroll
    for (int i = 0; i < 4; ++i) dst[(c0 + ty + 8 * i) * rows + r0 + tx] = f2bf(tile[tx][ty + 8 * i]);
}

// ---------------------------------------------------------------------------
// K1: LayerNorm fp32 -> bf16, one block (256 thr) per row of 1024
// ---------------------------------------------------------------------------
__global__ __launch_bounds__(256) void ln_kernel(const float* __restrict__ x,
                                                 const float* __restrict__ g,
                                                 const float* __restrict__ be,
                                                 unsigned short* __restrict__ xn) {
    int row = blockIdx.x, t = threadIdx.x;
    float4 v = ((const float4*)(x + row * Dd))[t];
    float s  = v.x + v.y + v.z + v.w;
    float sq = v.x * v.x + v.y * v.y + v.z * v.z + v.w * v.w;
#pragma unroll
    for (int off = 1; off < 64; off <<= 1) { s += __shfl_xor(s, off); sq += __shfl_xor(sq, off); }
    __shared__ float ps[4], pq2[4];
    int wv = t >> 6;
    if ((t & 63) == 0) { ps[wv] = s; pq2[wv] = sq; }
    __syncthreads();
    s  = ps[0] + ps[1] + ps[2] + ps[3];
    sq = pq2[0] + pq2[1] + pq2[2] + pq2[3];
    float mu   = s * (1.0f / Dd);
    float var  = sq * (1.0f / Dd) - mu * mu;
    float rstd = rsqrtf(var + 1e-5f);
    float4 gg = ((const float4*)g)[t];
    float4 bb = ((const float4*)be)[t];
    ushort4 o;
    o.x = f2bf((v.x - mu) * rstd * gg.x + bb.x);
    o.y = f2bf((v.y - mu) * rstd * gg.y + bb.y);
    o.z = f2bf((v.z - mu) * rstd * gg.z + bb.z);
    o.w = f2bf((v.w - mu) * rstd * gg.w + bb.w);
    ((ushort4*)(xn + row * Dd))[t] = o;
}

// ---------------------------------------------------------------------------
// K2: qkv GEMM v3 — 128x256 tile, 2-phase/K-tile counted-vmcnt schedule.
// [R7: left the top-5 (<74us, was 75.5). (512,1) = cap 256, no spill. Keep.]
// ---------------------------------------------------------------------------
__global__ __launch_bounds__(512, 1) void gemm_qkv(const unsigned short* __restrict__ A,
                                                   const unsigned short* __restrict__ Bt,
                                                   unsigned short* __restrict__ qo,
                                                   unsigned short* __restrict__ ko,
                                                   unsigned short* __restrict__ vo) {
    __shared__ unsigned short LDS[49152];   // 96 KiB: A[2][8192] @0, B[2][16384] @16384
    int r0 = blockIdx.x * 128, c0 = blockIdx.y * 256;
    int tid = threadIdx.x;
    int wv = tid >> 6, lane = tid & 63, l15 = lane & 15, quad = lane >> 4;
    int wm = wv >> 2, wn = wv & 3;          // 2M x 4N wave grid (64x64 each)

    floatx4 acc[4][4] = {};
    int swz0 = (quad ^ (l15 & 7)) << 3;            // k-chunk quad   (ks=0)
    int swz1 = ((4 | quad) ^ (l15 & 7)) << 3;      // k-chunk 4+quad (ks=1)

    auto stageA = [&](int tt) {                    // 16 KB: 2 loads/lane
        unsigned short* base = &LDS[(tt & 1) * 8192];
        int k0 = tt * 64;
#pragma unroll
        for (int i = 0; i < 2; ++i) {
            int qq = (wv * 2 + i) * 64 + lane;     // 0..1023 (16B units)
            int row = qq >> 3, cp = qq & 7;
            int sc = cp ^ (row & 7);
            load_lds16(&A[(r0 + row) * 1024 + k0 + sc * 8], &base[qq * 8]);
        }
    };
    auto stageB = [&](int tt) {                    // 32 KB: 4 loads/lane
        unsigned short* base = &LDS[16384 + (tt & 1) * 16384];
        int k0 = tt * 64;
#pragma unroll
        for (int i = 0; i < 4; ++i) {
            int qq = (wv * 4 + i) * 64 + lane;     // 0..2047 (16B units)
            int row = qq >> 3, cp = qq & 7;
            int sc = cp ^ (row & 7);
            load_lds16(&Bt[(c0 + row) * 1024 + k0 + sc * 8], &base[qq * 8]);
        }
    };

    // prologue: A(0) 2 + B(0) 4 + A(1) 2 loads; vmcnt(2) -> tile0 landed
    stageA(0); stageB(0); stageA(1);
    asm volatile("s_waitcnt vmcnt(2)" ::: "memory");
    __builtin_amdgcn_s_barrier();

    for (int t = 0; t < 16; ++t) {
        int abuf = (t & 1) * 8192;
        int bbuf = 16384 + (t & 1) * 16384;
        short8 af[4][2], bf[2][2];

        // ---- phase 0: wave cols 0..31 (ni 0,1) ----
        if (t < 15) stageB(t + 1);
#pragma unroll
        for (int mi = 0; mi < 4; ++mi) {
            af[mi][0] = *(const short8*)&LDS[abuf + (wm * 64 + mi * 16 + l15) * 64 + swz0];
            af[mi][1] = *(const short8*)&LDS[abuf + (wm * 64 + mi * 16 + l15) * 64 + swz1];
        }
#pragma unroll
        for (int ni = 0; ni < 2; ++ni) {
            bf[ni][0] = *(const short8*)&LDS[bbuf + (wn * 64 + ni * 16 + l15) * 64 + swz0];
            bf[ni][1] = *(const short8*)&LDS[bbuf + (wn * 64 + ni * 16 + l15) * 64 + swz1];
        }
        __builtin_amdgcn_s_barrier();
        asm volatile("s_waitcnt lgkmcnt(0)" ::: "memory");
        __builtin_amdgcn_s_setprio(1);
#pragma unroll
        for (int ks = 0; ks < 2; ++ks)
#pragma unroll
            for (int mi = 0; mi < 4; ++mi)
#pragma unroll
                for (int ni = 0; ni < 2; ++ni)
                    acc[mi][ni] = MFMA16(af[mi][ks], bf[ni][ks], acc[mi][ni]);
        __builtin_amdgcn_s_setprio(0);
        __builtin_amdgcn_s_barrier();

        // ---- phase 1: wave cols 32..63 (ni 2,3); af held in regs ----
        if (t < 14) stageA(t + 2);   // lands in CURRENT A-buf; A-reads done at ph0 barrier
#pragma unroll
        for (int ni = 0; ni < 2; ++ni) {
            bf[ni][0] = *(const short8*)&LDS[bbuf + (wn * 64 + 32 + ni * 16 + l15) * 64 + swz0];
            bf[ni][1] = *(const short8*)&LDS[bbuf + (wn * 64 + 32 + ni * 16 + l15) * 64 + swz1];
        }
        __builtin_amdgcn_s_barrier();
        asm volatile("s_waitcnt lgkmcnt(0)" ::: "memory");
        __builtin_amdgcn_s_setprio(1);
#pragma unroll
        for (int ks = 0; ks < 2; ++ks)
#pragma unroll
            for (int mi = 0; mi < 4; ++mi)
#pragma unroll
                for (int ni = 0; ni < 2; ++ni)
                    acc[mi][2 + ni] = MFMA16(af[mi][ks], bf[ni][ks], acc[mi][2 + ni]);
        __builtin_amdgcn_s_setprio(0);
        // counted vmcnt: retire A(t+1)+B(t+1) (needed by body t+1); leave
        // A(t+2) (2 loads) in flight across the barrier (T4).
        if (t < 14)       asm volatile("s_waitcnt vmcnt(2)" ::: "memory");
        else if (t == 14) asm volatile("s_waitcnt vmcnt(0)" ::: "memory");   // drain tail
        __builtin_amdgcn_s_barrier();
    }

    // ---- fused RoPE for q,k blocks (block-uniform branch) ----
    if (c0 < 2048) {
        const float crope = 13.287712379549449f / 32.0f;   // log2(10000)/32
        float invf0 = fast_exp2(-(float)l15 * crope);          // j = l15
        float invf1 = fast_exp2(-(float)(l15 + 16) * crope);   // j = 16+l15
#pragma unroll
        for (int mi = 0; mi < 4; ++mi)
#pragma unroll
            for (int r2 = 0; r2 < 4; ++r2) {
                int rr = r0 + wm * 64 + mi * 16 + quad * 4 + r2;
                float n = (float)(rr & 2047);
                float s0, c0r, s1, c1r;
                sincos_rev(n * invf0, s0, c0r);
                sincos_rev(n * invf1, s1, c1r);
                float t1a = acc[mi][0][r2], t2a = acc[mi][2][r2];
                acc[mi][0][r2] = t1a * c0r - t2a * s0;
                acc[mi][2][r2] = t2a * c0r + t1a * s0;
                float t1b = acc[mi][1][r2], t2b = acc[mi][3][r2];
                acc[mi][1][r2] = t1b * c1r - t2b * s1;
                acc[mi][3][r2] = t2b * c1r + t1b * s1;
            }
    }
    // q pre-scale: fold softmax scale*log2(e) into q so attn does raw exp2
    if (c0 < 1024) {
        const float qsc = 0.125f * 1.4426950408889634f;
#pragma unroll
        for (int mi = 0; mi < 4; ++mi)
#pragma unroll
            for (int ni = 0; ni < 4; ++ni)
#pragma unroll
                for (int r2 = 0; r2 < 4; ++r2) acc[mi][ni][r2] *= qsc;
    }
    // epilogue: C/D layout col = lane&15, row = quad*4 + reg (verified m89/m91)
    unsigned short* outp = (c0 < 1024) ? qo : (c0 < 2048) ? ko : vo;  // block-uniform
#pragma unroll
    for (int ni = 0; ni < 4; ++ni) {
        int c = c0 + wn * 64 + ni * 16 + l15;
        int cin = c & 1023;
        int h = cin >> 6, j = cin & 63;
#pragma unroll
        for (int mi = 0; mi < 4; ++mi) {
#pragma unroll
            for (int r2 = 0; r2 < 4; ++r2) {
                int rr = r0 + wm * 64 + mi * 16 + quad * 4 + r2;
                int b = rr >> 11, n = rr & 2047;
                int bh = b * 16 + h;
                outp[(bh * 2048 + n) * 64 + j] = f2bf(acc[mi][ni][r2]);
            }
        }
    }
}

// ---------------------------------------------------------------------------
// K2b: v [bh][n][hd] -> vt [bh][hd][n], key columns PERMUTED within each
// 32-key block: position p = 8q+4h+r holds key 16h+4q+r (matches the K=32
// PV A-fragment k-order in attn_kernel). [R8/R9: numerically verified]
// ---------------------------------------------------------------------------
__global__ __launch_bounds__(256) void vtrans(const unsigned short* __restrict__ v,
                                              unsigned short* __restrict__ vt) {
    __shared__ unsigned short T[64][72];
    int bh = blockIdx.y, n0 = blockIdx.x * 64;
    int t = threadIdx.x;
    int nl = t >> 2, c = (t & 3) * 16;
    const unsigned short* src = v + ((bh * 2048) + n0 + nl) * 64 + c;
    *(short8*)&T[nl][c]     = *(const short8*)src;
    *(short8*)&T[nl][c + 8] = *(const short8*)(src + 8);
    __syncthreads();
    int hd = t >> 2, nc = (t & 3) * 16;
    unsigned short tmp[16];
#pragma unroll
    for (int i = 0; i < 16; ++i) {
        int pos = nc + i;
        int blk = pos >> 5, p = pos & 31;
        int kq = (p >> 3) & 3, hh = (p >> 2) & 1, r = p & 3;
        tmp[i] = T[blk * 32 + hh * 16 + kq * 4 + r][hd];
    }
    unsigned short* dst = vt + ((bh * 64) + hd) * 2048 + n0 + nc;
    *(short8*)dst       = *(const short8*)&tmp[0];
    *(short8*)(dst + 8) = *(const short8*)&tmp[8];
}

// ---------------------------------------------------------------------------
// K4: flash attention v14b. R8 failure was NOT the structure: (256,4) means
// VGPR cap 64 (see model at top) -> accumulator spill, 1.05GB scratch writes,
// 331us. v14b: identical body, __launch_bounds__(256,2) -> cap 128 >= live
// set (65..84, R7-proven). 4 waves/SIMD x 128 VGPR = full 512-unit budget ->
// 4 blocks/CU co-residency (LDS 32K allows 5); grid 1024 = 4/CU, zero tail.
// ---------------------------------------------------------------------------
__global__ __launch_bounds__(256, 2) void attn_kernel(const unsigned short* __restrict__ q,
                                                      const unsigned short* __restrict__ k,
                                                      const unsigned short* __restrict__ vt,
                                                      unsigned short* __restrict__ attn) {
    __shared__ unsigned short KVs[2][2][64 * 64];  // [buf][K/V][row*64+swizzled] 32 KiB
    // XCD-affine decode: fid%8 = XCD (dispatch round-robin); each XCD owns
    // bh = {c, c+8, ..., c+56} and walks qi fastest -> K/V L2-resident. [R3 ✓]
    int fid = blockIdx.x;
    int xcd = fid & 7, rest = fid >> 3;
    int qi = rest & 15, bhg = rest >> 4;
    int bh = bhg * 8 + xcd;
    int q0 = qi * 128;
    int tid = threadIdx.x;
    int wave = tid >> 6, lane = tid & 63, l15 = lane & 15, quad = lane >> 4;
    const unsigned short* qb  = q  + bh * (Nn * HDd);
    const unsigned short* kbp = k  + bh * (Nn * HDd);
    const unsigned short* vb  = vt + bh * (HDd * Nn);   // [hd][n], key-permuted
    int qbase = q0 + wave * 32;

    // Q fragments (B-operand of 16x16x32), 2 groups of 16 q-rows per wave
    short8 bq[2][2];
#pragma unroll
    for (int g = 0; g < 2; ++g) {
        bq[g][0] = *(const short8*)&qb[(qbase + g * 16 + l15) * 64 + quad * 8];
        bq[g][1] = *(const short8*)&qb[(qbase + g * 16 + l15) * 64 + 32 + quad * 8];
    }

    // 4 waves stage 16 KB (K 8 KB + V 8 KB): 2 K + 2 V loads per lane
    auto stage = [&](int buf, int kb0) {
#pragma unroll
        for (int i = 0; i < 2; ++i) {
            int c = wave * 2 + i;
            int p = c * 64 + lane;
            int row = p >> 3, pr = p & 7;
            int sc = pr ^ (row & 7);                       // XOR chunk swizzle
            load_lds16(&kbp[(kb0 + row) * 64 + sc * 8], &KVs[buf][0][p * 8]);
            load_lds16(&vb[row * Nn + kb0 + sc * 8],    &KVs[buf][1][p * 8]);
        }
    };

    floatx4 ot[2][4] = {};                 // [g][ht]: O[q=quad*4+r][hd=ht*16+l15]
    floatx4 osum[2] = {};                  // row-sum of P via ones-MFMA; same row map
    const floatx4 fz = {0.0f, 0.0f, 0.0f, 0.0f};
    const short8 vones = {(short)0x3F80, (short)0x3F80, (short)0x3F80, (short)0x3F80,
                          (short)0x3F80, (short)0x3F80, (short)0x3F80, (short)0x3F80};
    int swz0 = (quad ^ (l15 & 7)) << 3;                    // chunk quad   (c=0)
    int swz1 = ((4 | quad) ^ (l15 & 7)) << 3;              // chunk 4+quad (c=1)

    // body(cur, kt): compute tile kt from KVs[cur]; stage kt+1 into cur^1
    // (buffer last read at body kt-1 — its end barrier separates).
    auto body = [&](int cur, int kt) {
        if (kt < 31) stage(cur ^ 1, (kt + 1) * 64);
        const unsigned short* Kc = KVs[cur][0];
        const unsigned short* Vc = KVs[cur][1];
        // ---- S^T = K.Q^T ----
        short8 ka0[4], ka1[4];
#pragma unroll
        for (int mb = 0; mb < 4; ++mb) {
            ka0[mb] = *(const short8*)&Kc[(mb * 16 + l15) * 64 + swz0];
            ka1[mb] = *(const short8*)&Kc[(mb * 16 + l15) * 64 + swz1];
        }
        short8 bv0[4], bv1[4];
#pragma unroll
        for (int ht = 0; ht < 4; ++ht) {
            int row = (ht * 16 + l15) * 64;
            bv0[ht] = *(const short8*)&Vc[row + swz0];
            bv1[ht] = *(const short8*)&Vc[row + swz1];
        }
#pragma unroll
        for (int g = 0; g < 2; ++g) {
            floatx4 st[4];
            __builtin_amdgcn_s_setprio(1);
#pragma unroll
            for (int mb = 0; mb < 4; ++mb) {
                floatx4 z = MFMA16(ka0[mb], bq[g][0], fz);
                st[mb] = MFMA16(ka1[mb], bq[g][1], z);
            }
            __builtin_amdgcn_s_setprio(0);
            // ---- P = exp2(S) (q pre-scaled); pack K=32 A-fragments ----
            short8 pa[2];
#pragma unroll
            for (int c = 0; c < 2; ++c) {
                union { ushort4 u[2]; short8 s; } w;
#pragma unroll
                for (int t2 = 0; t2 < 2; ++t2) {
                    int mb = 2 * c + t2;
                    float p0 = fast_exp2(st[mb][0]);
                    float p1 = fast_exp2(st[mb][1]);
                    float p2 = fast_exp2(st[mb][2]);
                    float p3 = fast_exp2(st[mb][3]);
                    *(__hip_bfloat162*)&w.u[t2].x = __float22bfloat162_rn(float2{p0, p1});
                    *(__hip_bfloat162*)&w.u[t2].z = __float22bfloat162_rn(float2{p2, p3});
                }
                pa[c] = w.s;
            }
            // ---- O[q][hd] += P.V ; denom += P.1  (all in matrix pipe) ----
            __builtin_amdgcn_s_setprio(1);
            osum[g] = MFMA16(pa[0], vones, osum[g]);
            osum[g] = MFMA16(pa[1], vones, osum[g]);
#pragma unroll
            for (int ht = 0; ht < 4; ++ht) {
                ot[g][ht] = MFMA16(pa[0], bv0[ht], ot[g][ht]);
                ot[g][ht] = MFMA16(pa[1], bv1[ht], ot[g][ht]);
            }
            __builtin_amdgcn_s_setprio(0);
        }
        // drain this body's stage (issued ~600cyc ago, L2-resident) so the
        // block can read buf cur^1 next body; barrier promotes block-wide.
        if (kt < 31) asm volatile("s_waitcnt vmcnt(0)" ::: "memory");
        __builtin_amdgcn_s_barrier();
    };

    stage(0, 0);
    asm volatile("s_waitcnt vmcnt(0)" ::: "memory");   // tile 0 landed
    __builtin_amdgcn_s_barrier();
    for (int kt = 0; kt < 32; kt += 2) {
        body(0, kt);
        body(1, kt + 1);
    }

    // ---- epilogue: invl directly from osum (same row map as ot) ----
    int b = bh >> 4, h = bh & 15;
    unsigned short* ob = ((unsigned short*)KVs) + wave * 1152;   // 16 rows x 72
#pragma unroll
    for (int g = 0; g < 2; ++g) {
        float il[4];
#pragma unroll
        for (int r = 0; r < 4; ++r) il[r] = 1.0f / osum[g][r];
#pragma unroll
        for (int ht = 0; ht < 4; ++ht)
#pragma unroll
            for (int r = 0; r < 4; ++r)
                ob[(quad * 4 + r) * 72 + ht * 16 + l15] = f2bf(ot[g][ht][r] * il[r]);
        // wave-private region: ds_write -> ds_read ordered by lgkmcnt within wave
        int q_loc = lane >> 2, seg = lane & 3;
        unsigned short* dst = attn + ((long)(b * Nn + q0 + wave * 32 + g * 16 + q_loc)) * 1024 + h * 64 + seg * 16;
        *(short8*)dst       = *(const short8*)&ob[q_loc * 72 + seg * 16];
        *(short8*)(dst + 8) = *(const short8*)&ob[q_loc * 72 + seg * 16 + 8];
    }
}

// ---------------------------------------------------------------------------
// K5: out-projection v2 — gemm_qkv v3 structure (128x256, 2-phase, counted
// vmcnt). Grid 64x4 = 256 blocks = exactly 1 round at 1 block/CU.
// ---------------------------------------------------------------------------
__global__ __launch_bounds__(512, 1) void gemm_out(const unsigned short* __restrict__ A,
                                                   const unsigned short* __restrict__ Bt,
                                                   const float* __restrict__ bout,
                                                   float* __restrict__ out) {
    __shared__ unsigned short LDS[49152];   // 96 KiB: A[2][8192] @0, B[2][16384] @16384
    int r0 = blockIdx.x * 128, c0 = blockIdx.y * 256;
    int tid = threadIdx.x;
    int wv = tid >> 6, lane = tid & 63, l15 = lane & 15, quad = lane >> 4;
    int wm = wv >> 2, wn = wv & 3;          // 2M x 4N wave grid (64x64 each)

    floatx4 acc[4][4] = {};
    int swz0 = (quad ^ (l15 & 7)) << 3;
    int swz1 = ((4 | quad) ^ (l15 & 7)) << 3;

    auto stageA = [&](int tt) {
        unsigned short* base = &LDS[(tt & 1) * 8192];
        int k0 = tt * 64;
#pragma unroll
        for (int i = 0; i < 2; ++i) {
            int qq = (wv * 2 + i) * 64 + lane;
            int row = qq >> 3, cp = qq & 7;
            int sc = cp ^ (row & 7);
            load_lds16(&A[(r0 + row) * 1024 + k0 + sc * 8], &base[qq * 8]);
        }
    };
    auto stageB = [&](int tt) {
        unsigned short* base = &LDS[16384 + (tt & 1) * 16384];
        int k0 = tt * 64;
#pragma unroll
        for (int i = 0; i < 4; ++i) {
            int qq = (wv * 4 + i) * 64 + lane;
            int row = qq >> 3, cp = qq & 7;
            int sc = cp ^ (row & 7);
            load_lds16(&Bt[(c0 + row) * 1024 + k0 + sc * 8], &base[qq * 8]);
        }
    };

    stageA(0); stageB(0); stageA(1);
    asm volatile("s_waitcnt vmcnt(2)" ::: "memory");
    __builtin_amdgcn_s_barrier();

    for (int t = 0; t < 16; ++t) {
        int abuf = (t & 1) * 8192;
        int bbuf = 16384 + (t & 1) * 16384;
        short8 af[4][2], bf[2][2];

        // ---- phase 0 ----
        if (t < 15) stageB(t + 1);
#pragma unroll
        for (int mi = 0; mi < 4; ++mi) {
            af[mi][0] = *(const short8*)&LDS[abuf + (wm * 64 + mi * 16 + l15) * 64 + swz0];
            af[mi][1] = *(const short8*)&LDS[abuf + (wm * 64 + mi * 16 + l15) * 64 + swz1];
        }
#pragma unroll
        for (int ni = 0; ni < 2; ++ni) {
            bf[ni][0] = *(const short8*)&LDS[bbuf + (wn * 64 + ni * 16 + l15) * 64 + swz0];
            bf[ni][1] = *(const short8*)&LDS[bbuf + (wn * 64 + ni * 16 + l15) * 64 + swz1];
        }
        __builtin_amdgcn_s_barrier();
        asm volatile("s_waitcnt lgkmcnt(0)" ::: "memory");
        __builtin_amdgcn_s_setprio(1);
#pragma unroll
        for (int ks = 0; ks < 2; ++ks)
#pragma unroll
            for (int mi = 0; mi < 4; ++mi)
#pragma unroll
                for (int ni = 0; ni < 2; ++ni)
                    acc[mi][ni] = MFMA16(af[mi][ks], bf[ni][ks], acc[mi][ni]);
        __builtin_amdgcn_s_setprio(0);
        __builtin_amdgcn_s_barrier();

        // ---- phase 1 ----
        if (t < 14) stageA(t + 2);
#pragma unroll
        for (int ni = 0; ni < 2; ++ni) {
            bf[ni][0] = *(const short8*)&LDS[bbuf + (wn * 64 + 32 + ni * 16 + l15) * 64 + swz0];
            bf[ni][1] = *(const short8*)&LDS[bbuf + (wn * 64 + 32 + ni * 16 + l15) * 64 + swz1];
        }
        __builtin_amdgcn_s_barrier();
        asm volatile("s_waitcnt lgkmcnt(0)" ::: "memory");
        __builtin_amdgcn_s_setprio(1);
#pragma unroll
        for (int ks = 0; ks < 2; ++ks)
#pragma unroll
            for (int mi = 0; mi < 4; ++mi)
#pragma unroll
                for (int ni = 0; ni < 2; ++ni)
                    acc[mi][2 + ni] = MFMA16(af[mi][ks], bf[ni][ks], acc[mi][2 + ni]);
        __builtin_amdgcn_s_setprio(0);
        if (t < 14)       asm volatile("s_waitcnt vmcnt(2)" ::: "memory");
        else if (t == 14) asm volatile("s_waitcnt vmcnt(0)" ::: "memory");
        __builtin_amdgcn_s_barrier();
    }

#pragma unroll
    for (int ni = 0; ni < 4; ++ni) {
        int c = c0 + wn * 64 + ni * 16 + l15;
        float bias = bout[c];
#pragma unroll
        for (int mi = 0; mi < 4; ++mi)
#pragma unroll
            for (int r2 = 0; r2 < 4; ++r2) {
                int rr = r0 + wm * 64 + mi * 16 + quad * 4 + r2;
                out[rr * 1024 + c] = acc[mi][ni][r2] + bias;
            }
    }
}

// ---------------------------------------------------------------------------
extern "C" void kernel_launch(void* const* d_in, const int* in_sizes, int n_in,
                              void* d_out, int out_size, void* d_ws, size_t ws_size,
                              hipStream_t stream) {
    const float* x    = (const float*)d_in[0];
    const float* g    = (const float*)d_in[1];
    const float* be   = (const float*)d_in[2];
    const float* wqkv = (const float*)d_in[3];
    const float* wout = (const float*)d_in[4];
    const float* bout = (const float*)d_in[5];
    float* out = (float*)d_out;

    char* ws = (char*)d_ws;
    unsigned short* xn    = (unsigned short*)(ws);                 // 16 MB
    unsigned short* wqkvT = (unsigned short*)(ws + 16777216);      //  6 MB
    unsigned short* woutT = (unsigned short*)(ws + 23068672);      //  2 MB
    unsigned short* qb    = (unsigned short*)(ws + 25165824);      // 16 MB
    unsigned short* kb    = (unsigned short*)(ws + 41943040);      // 16 MB
    unsigned short* vt    = (unsigned short*)(ws + 58720256);      // 16 MB
    unsigned short* attn  = (unsigned short*)(ws + 75497472);      // 16 MB
    unsigned short* vtmp  = attn;   // v row-layout parks in attn buffer

    transpose_w<<<dim3(IN3 / 32, Dd / 32), dim3(32, 8), 0, stream>>>(wqkv, wqkvT, Dd, IN3);
    transpose_w<<<dim3(Dd / 32, Dd / 32), dim3(32, 8), 0, stream>>>(wout, woutT, Dd, Dd);
    ln_kernel<<<RR, 256, 0, stream>>>(x, g, be, xn);
    gemm_qkv<<<dim3(RR / 128, IN3 / 256), 512, 0, stream>>>(xn, wqkvT, qb, kb, vtmp);
    vtrans<<<dim3(Nn / 64, Bb * Hh), 256, 0, stream>>>(vtmp, vt);
    attn_kernel<<<dim3(Nn / 128 * Bb * Hh), 256, 0, stream>>>(qb, kb, vt, attn);
    gemm_out<<<dim3(RR / 128, Dd / 256), 512, 0, stream>>>(attn, woutT, bout, out);
}

// Round 10
// 254.302 us; speedup vs baseline: 2.0801x; 1.0235x over previous
//
#include <hip/hip_runtime.h>
#include <hip/hip_bf16.h>

// Problem constants
#define Bb   4
#define Nn   2048
#define Dd   1024
#define Hh   16
#define HDd  64
#define IN3  3072          // 3 * H * HD
#define RR   8192          // B * N

// ---------------------------------------------------------------------------
// __launch_bounds__ EMPIRICAL MODEL (this compiler, gfx950) — R2/R5/R8 data:
//   VGPR cap = 512 / (2 * arg2) = 256 / arg2, INDEPENDENT of block size.
//   (512,1)->256  (512,2)->128  (256,2)->128  (256,3)->85  (256,4)->64
// Compiler allocates UP TO cap; exceeding it = scratch spill (WRITE_SIZE
// blow-up: 625MB R2, 1.05GB R8). Occupancy knobs on attn: <5% effect
// (R3/R9) — attn is pipe-sum bound, not occupancy bound.
// ---------------------------------------------------------------------------

typedef __attribute__((ext_vector_type(8))) short short8;
typedef __attribute__((ext_vector_type(4))) float floatx4;

#define MFMA16(a, b, c) __builtin_amdgcn_mfma_f32_16x16x32_bf16((a), (b), (c), 0, 0, 0)

static __device__ __forceinline__ unsigned short f2bf(float f) {
    union { float f; unsigned int u; } v; v.f = f;
    unsigned int r = v.u + 0x7fffu + ((v.u >> 16) & 1u);   // RNE
    return (unsigned short)(r >> 16);
}
static __device__ __forceinline__ float bf2f(unsigned short h) {
    union { unsigned int u; float f; } v; v.u = ((unsigned int)h) << 16;
    return v.f;
}

// raw v_exp_f32 (args small; no OCML fixup needed) [R6 win]
static __device__ __forceinline__ float fast_exp2(float x) {
#if __has_builtin(__builtin_amdgcn_exp2f)
    return __builtin_amdgcn_exp2f(x);
#else
    return exp2f(x);
#endif
}

// sin/cos via v_fract + v_sin/v_cos (revolutions) [R10 win, fused rope]
static __device__ __forceinline__ void sincos_rev(float ang, float& s, float& c) {
#if __has_builtin(__builtin_amdgcn_sinf) && __has_builtin(__builtin_amdgcn_cosf)
    float rev = ang * 0.15915494309189535f;
    rev = rev - floorf(rev);
    s = __builtin_amdgcn_sinf(rev);
    c = __builtin_amdgcn_cosf(rev);
#else
    s = sinf(ang);
    c = cosf(ang);
#endif
}

// async global->LDS DMA, 16B/lane (validated in-session R5-R10)
typedef const __attribute__((address_space(1))) void* gas1_t;
typedef __attribute__((address_space(3))) void* las3_t;
static __device__ __forceinline__ void load_lds16(const void* g, void* l) {
    __builtin_amdgcn_global_load_lds((gas1_t)(unsigned long long)g,
                                     (las3_t)(unsigned int)(unsigned long long)l,
                                     16, 0, 0);
}

// ---------------------------------------------------------------------------
// K0: transpose fp32 [rows][cols] -> bf16 [cols][rows], BOTH weights in one
// launch (grid.z: 0 = w_qkv 1024x3072, 1 = w_out 1024x1024). [R10: one
// fewer dispatch — inter-kernel gaps measured ~8us each]
// ---------------------------------------------------------------------------
__global__ void transpose_w(const float* __restrict__ s0, unsigned short* __restrict__ d0,
                            const float* __restrict__ s1, unsigned short* __restrict__ d1) {
    const float* src; unsigned short* dst; int cols;
    if (blockIdx.z == 0) { src = s0; dst = d0; cols = 3072; }
    else { if (blockIdx.x >= 32) return; src = s1; dst = d1; cols = 1024; }  // block-uniform
    __shared__ float tile[32][33];
    int c0 = blockIdx.x * 32, r0 = blockIdx.y * 32;
    int tx = threadIdx.x, ty = threadIdx.y;   // 32 x 8
#pragma unroll
    for (int i = 0; i < 4; ++i) tile[ty + 8 * i][tx] = src[(r0 + ty + 8 * i) * cols + c0 + tx];
    __syncthreads();
#pragma unroll
    for (int i = 0; i < 4; ++i) dst[(c0 + ty + 8 * i) * 1024 + r0 + tx] = f2bf(tile[tx][ty + 8 * i]);
}

// ---------------------------------------------------------------------------
// K1: LayerNorm fp32 -> bf16, one block (256 thr) per row of 1024
// ---------------------------------------------------------------------------
__global__ __launch_bounds__(256) void ln_kernel(const float* __restrict__ x,
                                                 const float* __restrict__ g,
                                                 const float* __restrict__ be,
                                                 unsigned short* __restrict__ xn) {
    int row = blockIdx.x, t = threadIdx.x;
    float4 v = ((const float4*)(x + row * Dd))[t];
    float s  = v.x + v.y + v.z + v.w;
    float sq = v.x * v.x + v.y * v.y + v.z * v.z + v.w * v.w;
#pragma unroll
    for (int off = 1; off < 64; off <<= 1) { s += __shfl_xor(s, off); sq += __shfl_xor(sq, off); }
    __shared__ float ps[4], pq2[4];
    int wv = t >> 6;
    if ((t & 63) == 0) { ps[wv] = s; pq2[wv] = sq; }
    __syncthreads();
    s  = ps[0] + ps[1] + ps[2] + ps[3];
    sq = pq2[0] + pq2[1] + pq2[2] + pq2[3];
    float mu   = s * (1.0f / Dd);
    float var  = sq * (1.0f / Dd) - mu * mu;
    float rstd = rsqrtf(var + 1e-5f);
    float4 gg = ((const float4*)g)[t];
    float4 bb = ((const float4*)be)[t];
    ushort4 o;
    o.x = f2bf((v.x - mu) * rstd * gg.x + bb.x);
    o.y = f2bf((v.y - mu) * rstd * gg.y + bb.y);
    o.z = f2bf((v.z - mu) * rstd * gg.z + bb.z);
    o.w = f2bf((v.w - mu) * rstd * gg.w + bb.w);
    ((ushort4*)(xn + row * Dd))[t] = o;
}

// ---------------------------------------------------------------------------
// K2: qkv GEMM v4 — 128x256 tile, 2-phase/K-tile counted-vmcnt schedule
// [R7-proven]. NEW (R10): vtrans FUSED into the v-epilogue — v-blocks
// (c0>=2048) transpose their 128x256 tile through LDS (free post-loop) and
// write vt[bh][hd][n] directly with the within-32 key permutation:
//   dst pos p (in 32-block)  <-  src row 16*((p>>2)&1) + 4*((p>>3)&3) + (p&3)
// (algebraically identical to the old vtrans kernel). Kills the vtrans
// dispatch + 32MB of intermediate HBM traffic.
// ---------------------------------------------------------------------------
__global__ __launch_bounds__(512, 1) void gemm_qkv(const unsigned short* __restrict__ A,
                                                   const unsigned short* __restrict__ Bt,
                                                   unsigned short* __restrict__ qo,
                                                   unsigned short* __restrict__ ko,
                                                   unsigned short* __restrict__ vo) {
    __shared__ unsigned short LDS[49152];   // 96 KiB: A[2][8192] @0, B[2][16384] @16384
    int r0 = blockIdx.x * 128, c0 = blockIdx.y * 256;
    int tid = threadIdx.x;
    int wv = tid >> 6, lane = tid & 63, l15 = lane & 15, quad = lane >> 4;
    int wm = wv >> 2, wn = wv & 3;          // 2M x 4N wave grid (64x64 each)

    floatx4 acc[4][4] = {};
    int swz0 = (quad ^ (l15 & 7)) << 3;            // k-chunk quad   (ks=0)
    int swz1 = ((4 | quad) ^ (l15 & 7)) << 3;      // k-chunk 4+quad (ks=1)

    auto stageA = [&](int tt) {                    // 16 KB: 2 loads/lane
        unsigned short* base = &LDS[(tt & 1) * 8192];
        int k0 = tt * 64;
#pragma unroll
        for (int i = 0; i < 2; ++i) {
            int qq = (wv * 2 + i) * 64 + lane;     // 0..1023 (16B units)
            int row = qq >> 3, cp = qq & 7;
            int sc = cp ^ (row & 7);
            load_lds16(&A[(r0 + row) * 1024 + k0 + sc * 8], &base[qq * 8]);
        }
    };
    auto stageB = [&](int tt) {                    // 32 KB: 4 loads/lane
        unsigned short* base = &LDS[16384 + (tt & 1) * 16384];
        int k0 = tt * 64;
#pragma unroll
        for (int i = 0; i < 4; ++i) {
            int qq = (wv * 4 + i) * 64 + lane;     // 0..2047 (16B units)
            int row = qq >> 3, cp = qq & 7;
            int sc = cp ^ (row & 7);
            load_lds16(&Bt[(c0 + row) * 1024 + k0 + sc * 8], &base[qq * 8]);
        }
    };

    // prologue: A(0) 2 + B(0) 4 + A(1) 2 loads; vmcnt(2) -> tile0 landed
    stageA(0); stageB(0); stageA(1);
    asm volatile("s_waitcnt vmcnt(2)" ::: "memory");
    __builtin_amdgcn_s_barrier();

    for (int t = 0; t < 16; ++t) {
        int abuf = (t & 1) * 8192;
        int bbuf = 16384 + (t & 1) * 16384;
        short8 af[4][2], bf[2][2];

        // ---- phase 0: wave cols 0..31 (ni 0,1) ----
        if (t < 15) stageB(t + 1);
#pragma unroll
        for (int mi = 0; mi < 4; ++mi) {
            af[mi][0] = *(const short8*)&LDS[abuf + (wm * 64 + mi * 16 + l15) * 64 + swz0];
            af[mi][1] = *(const short8*)&LDS[abuf + (wm * 64 + mi * 16 + l15) * 64 + swz1];
        }
#pragma unroll
        for (int ni = 0; ni < 2; ++ni) {
            bf[ni][0] = *(const short8*)&LDS[bbuf + (wn * 64 + ni * 16 + l15) * 64 + swz0];
            bf[ni][1] = *(const short8*)&LDS[bbuf + (wn * 64 + ni * 16 + l15) * 64 + swz1];
        }
        __builtin_amdgcn_s_barrier();
        asm volatile("s_waitcnt lgkmcnt(0)" ::: "memory");
        __builtin_amdgcn_s_setprio(1);
#pragma unroll
        for (int ks = 0; ks < 2; ++ks)
#pragma unroll
            for (int mi = 0; mi < 4; ++mi)
#pragma unroll
                for (int ni = 0; ni < 2; ++ni)
                    acc[mi][ni] = MFMA16(af[mi][ks], bf[ni][ks], acc[mi][ni]);
        __builtin_amdgcn_s_setprio(0);
        __builtin_amdgcn_s_barrier();

        // ---- phase 1: wave cols 32..63 (ni 2,3); af held in regs ----
        if (t < 14) stageA(t + 2);   // lands in CURRENT A-buf; A-reads done at ph0 barrier
#pragma unroll
        for (int ni = 0; ni < 2; ++ni) {
            bf[ni][0] = *(const short8*)&LDS[bbuf + (wn * 64 + 32 + ni * 16 + l15) * 64 + swz0];
            bf[ni][1] = *(const short8*)&LDS[bbuf + (wn * 64 + 32 + ni * 16 + l15) * 64 + swz1];
        }
        __builtin_amdgcn_s_barrier();
        asm volatile("s_waitcnt lgkmcnt(0)" ::: "memory");
        __builtin_amdgcn_s_setprio(1);
#pragma unroll
        for (int ks = 0; ks < 2; ++ks)
#pragma unroll
            for (int mi = 0; mi < 4; ++mi)
#pragma unroll
                for (int ni = 0; ni < 2; ++ni)
                    acc[mi][2 + ni] = MFMA16(af[mi][ks], bf[ni][ks], acc[mi][2 + ni]);
        __builtin_amdgcn_s_setprio(0);
        // counted vmcnt: retire A(t+1)+B(t+1) (needed by body t+1); leave
        // A(t+2) (2 loads) in flight across the barrier (T4).
        if (t < 14)       asm volatile("s_waitcnt vmcnt(2)" ::: "memory");
        else if (t == 14) asm volatile("s_waitcnt vmcnt(0)" ::: "memory");   // drain tail
        __builtin_amdgcn_s_barrier();
    }

    if (c0 >= 2048) {
        // ---- fused V epilogue: transpose + kperm through LDS -> vt ----
        // T2[col][row], stride 136 rows (bank-spread); 256*136 shorts = 68KB.
        // All waves passed the loop-end barrier after their own lgkmcnt(0),
        // so LDS is free to overwrite.
        unsigned short* T2 = LDS;
#pragma unroll
        for (int mi = 0; mi < 4; ++mi)
#pragma unroll
            for (int ni = 0; ni < 4; ++ni) {
                ushort4 w4;
                w4.x = f2bf(acc[mi][ni][0]);
                w4.y = f2bf(acc[mi][ni][1]);
                w4.z = f2bf(acc[mi][ni][2]);
                w4.w = f2bf(acc[mi][ni][3]);
                int col = wn * 64 + ni * 16 + l15;             // v-col (0..255)
                int row = wm * 64 + mi * 16 + quad * 4;        // local n (0..124, mult of 4)
                *(ushort4*)&T2[col * 136 + row] = w4;
            }
        __syncthreads();
        // gather permuted 4-row runs; each thread owns (col, 64-n segment)
        int col = tid >> 1, seg = tid & 1;
        int hglob = ((c0 - 2048) >> 6) + (col >> 6);           // head 0..15
        int j = col & 63;
        int b = r0 >> 11;
        int n0g = (r0 & 2047) + seg * 64;
        unsigned short tmp[64];
#pragma unroll
        for (int gi = 0; gi < 16; ++gi) {
            int blk = seg * 2 + (gi >> 3);
            int srow = blk * 32 + 16 * (gi & 1) + 4 * ((gi >> 1) & 3);
            *(ushort4*)&tmp[gi * 4] = *(const ushort4*)&T2[col * 136 + srow];
        }
        unsigned short* dst = vo + (((long)(b * 16 + hglob)) * 64 + j) * 2048 + n0g;
#pragma unroll
        for (int k2 = 0; k2 < 8; ++k2)
            *(short8*)(dst + k2 * 8) = *(const short8*)&tmp[k2 * 8];
        return;
    }

    // ---- fused RoPE for q,k blocks (block-uniform branch; c0 < 2048) ----
    {
        const float crope = 13.287712379549449f / 32.0f;   // log2(10000)/32
        float invf0 = fast_exp2(-(float)l15 * crope);          // j = l15
        float invf1 = fast_exp2(-(float)(l15 + 16) * crope);   // j = 16+l15
#pragma unroll
        for (int mi = 0; mi < 4; ++mi)
#pragma unroll
            for (int r2 = 0; r2 < 4; ++r2) {
                int rr = r0 + wm * 64 + mi * 16 + quad * 4 + r2;
                float n = (float)(rr & 2047);
                float s0, c0r, s1, c1r;
                sincos_rev(n * invf0, s0, c0r);
                sincos_rev(n * invf1, s1, c1r);
                float t1a = acc[mi][0][r2], t2a = acc[mi][2][r2];
                acc[mi][0][r2] = t1a * c0r - t2a * s0;
                acc[mi][2][r2] = t2a * c0r + t1a * s0;
                float t1b = acc[mi][1][r2], t2b = acc[mi][3][r2];
                acc[mi][1][r2] = t1b * c1r - t2b * s1;
                acc[mi][3][r2] = t2b * c1r + t1b * s1;
            }
    }
    // q pre-scale: fold softmax scale*log2(e) into q so attn does raw exp2
    if (c0 < 1024) {
        const float qsc = 0.125f * 1.4426950408889634f;
#pragma unroll
        for (int mi = 0; mi < 4; ++mi)
#pragma unroll
            for (int ni = 0; ni < 4; ++ni)
#pragma unroll
                for (int r2 = 0; r2 < 4; ++r2) acc[mi][ni][r2] *= qsc;
    }
    // epilogue: C/D layout col = lane&15, row = quad*4 + reg (verified m89/m91)
    unsigned short* outp = (c0 < 1024) ? qo : ko;   // block-uniform
#pragma unroll
    for (int ni = 0; ni < 4; ++ni) {
        int c = c0 + wn * 64 + ni * 16 + l15;
        int cin = c & 1023;
        int h = cin >> 6, j = cin & 63;
#pragma unroll
        for (int mi = 0; mi < 4; ++mi) {
#pragma unroll
            for (int r2 = 0; r2 < 4; ++r2) {
                int rr = r0 + wm * 64 + mi * 16 + quad * 4 + r2;
                int b = rr >> 11, n = rr & 2047;
                int bh = b * 16 + h;
                outp[(bh * 2048 + n) * 64 + j] = f2bf(acc[mi][ni][r2]);
            }
        }
    }
}

// ---------------------------------------------------------------------------
// K4: flash attention v13 (R7 config — best measured attn, 74.2us; R9's
// 2-deep vmcnt(0)-per-body variant was 77.5us, reverted).
//  (1) denominator via ones-column MFMA (osum).
//  (2) 3-deep KV rotation + counted s_waitcnt vmcnt(4) + raw s_barrier.
//  (3) setprio(1) around MFMA clusters (T5).
//  (4) persistent zero C-in vector.
// ---------------------------------------------------------------------------
__global__ __launch_bounds__(256, 3) void attn_kernel(const unsigned short* __restrict__ q,
                                                      const unsigned short* __restrict__ k,
                                                      const unsigned short* __restrict__ vt,
                                                      unsigned short* __restrict__ attn) {
    __shared__ unsigned short KVs[3][2][64 * 64];  // [buf][K/V][row*64+swizzled] 48 KiB
    // XCD-affine decode: fid%8 = XCD (dispatch round-robin); each XCD owns
    // bh = {c, c+8, ..., c+56} and walks qi fastest -> K/V L2-resident. [R3 ✓]
    int fid = blockIdx.x;
    int xcd = fid & 7, rest = fid >> 3;
    int qi = rest & 15, bhg = rest >> 4;
    int bh = bhg * 8 + xcd;
    int q0 = qi * 128;
    int tid = threadIdx.x;
    int wave = tid >> 6, lane = tid & 63, l15 = lane & 15, quad = lane >> 4;
    const unsigned short* qb  = q  + bh * (Nn * HDd);
    const unsigned short* kbp = k  + bh * (Nn * HDd);
    const unsigned short* vb  = vt + bh * (HDd * Nn);   // [hd][n], key-permuted
    int qbase = q0 + wave * 32;

    // Q fragments (B-operand of 16x16x32), 2 groups of 16 q-rows per wave
    short8 bq[2][2];
#pragma unroll
    for (int g = 0; g < 2; ++g) {
        bq[g][0] = *(const short8*)&qb[(qbase + g * 16 + l15) * 64 + quad * 8];
        bq[g][1] = *(const short8*)&qb[(qbase + g * 16 + l15) * 64 + 32 + quad * 8];
    }

    // 4 waves stage 16 KB (K 8 KB + V 8 KB): 2 K + 2 V loads per lane
    auto stage = [&](int buf, int kb0) {
#pragma unroll
        for (int i = 0; i < 2; ++i) {
            int c = wave * 2 + i;
            int p = c * 64 + lane;
            int row = p >> 3, pr = p & 7;
            int sc = pr ^ (row & 7);                       // XOR chunk swizzle
            load_lds16(&kbp[(kb0 + row) * 64 + sc * 8], &KVs[buf][0][p * 8]);
            load_lds16(&vb[row * Nn + kb0 + sc * 8],    &KVs[buf][1][p * 8]);
        }
    };

    floatx4 ot[2][4] = {};                 // [g][ht]: O[q=quad*4+r][hd=ht*16+l15]
    floatx4 osum[2] = {};                  // row-sum of P via ones-MFMA; same row map
    const floatx4 fz = {0.0f, 0.0f, 0.0f, 0.0f};
    const short8 vones = {(short)0x3F80, (short)0x3F80, (short)0x3F80, (short)0x3F80,
                          (short)0x3F80, (short)0x3F80, (short)0x3F80, (short)0x3F80};
    int swz0 = (quad ^ (l15 & 7)) << 3;                    // chunk quad   (c=0)
    int swz1 = ((4 | quad) ^ (l15 & 7)) << 3;              // chunk 4+quad (c=1)

    // body(cur, nxt, kt): compute tile kt from KVs[cur]; stage kt+2 into
    // KVs[nxt] (= buffer read at kt-1: all waves past that read via barrier).
    auto body = [&](int cur, int nxt, int kt) {
        if (kt + 2 < 32) stage(nxt, (kt + 2) * 64);
        const unsigned short* Kc = KVs[cur][0];
        const unsigned short* Vc = KVs[cur][1];
        // ---- S^T = K.Q^T ----
        short8 ka0[4], ka1[4];
#pragma unroll
        for (int mb = 0; mb < 4; ++mb) {
            ka0[mb] = *(const short8*)&Kc[(mb * 16 + l15) * 64 + swz0];
            ka1[mb] = *(const short8*)&Kc[(mb * 16 + l15) * 64 + swz1];
        }
        short8 bv0[4], bv1[4];
#pragma unroll
        for (int ht = 0; ht < 4; ++ht) {
            int row = (ht * 16 + l15) * 64;
            bv0[ht] = *(const short8*)&Vc[row + swz0];
            bv1[ht] = *(const short8*)&Vc[row + swz1];
        }
#pragma unroll
        for (int g = 0; g < 2; ++g) {
            floatx4 st[4];
            __builtin_amdgcn_s_setprio(1);
#pragma unroll
            for (int mb = 0; mb < 4; ++mb) {
                floatx4 z = MFMA16(ka0[mb], bq[g][0], fz);
                st[mb] = MFMA16(ka1[mb], bq[g][1], z);
            }
            __builtin_amdgcn_s_setprio(0);
            // ---- P = exp2(S) (q pre-scaled); pack K=32 A-fragments ----
            short8 pa[2];
#pragma unroll
            for (int c = 0; c < 2; ++c) {
                union { ushort4 u[2]; short8 s; } w;
#pragma unroll
                for (int t2 = 0; t2 < 2; ++t2) {
                    int mb = 2 * c + t2;
                    float p0 = fast_exp2(st[mb][0]);
                    float p1 = fast_exp2(st[mb][1]);
                    float p2 = fast_exp2(st[mb][2]);
                    float p3 = fast_exp2(st[mb][3]);
                    *(__hip_bfloat162*)&w.u[t2].x = __float22bfloat162_rn(float2{p0, p1});
                    *(__hip_bfloat162*)&w.u[t2].z = __float22bfloat162_rn(float2{p2, p3});
                }
                pa[c] = w.s;
            }
            // ---- O[q][hd] += P.V ; denom += P.1  (all in matrix pipe) ----
            __builtin_amdgcn_s_setprio(1);
            osum[g] = MFMA16(pa[0], vones, osum[g]);
            osum[g] = MFMA16(pa[1], vones, osum[g]);
#pragma unroll
            for (int ht = 0; ht < 4; ++ht) {
                ot[g][ht] = MFMA16(pa[0], bv0[ht], ot[g][ht]);
                ot[g][ht] = MFMA16(pa[1], bv1[ht], ot[g][ht]);
            }
            __builtin_amdgcn_s_setprio(0);
        }
        // counted vmcnt: tile kt+1 (4 loads of kt+2 may stay in flight);
        // raw barrier — no vmcnt(0)/lgkmcnt(0) drain (T4).
        if (kt < 30)       asm volatile("s_waitcnt vmcnt(4)" ::: "memory");
        else if (kt == 30) asm volatile("s_waitcnt vmcnt(0)" ::: "memory");
        __builtin_amdgcn_s_barrier();
    };

    stage(0, 0);
    stage(1, 64);
    asm volatile("s_waitcnt vmcnt(4)" ::: "memory");   // tile 0 landed
    __builtin_amdgcn_s_barrier();
    for (int kt = 0; kt < 30; kt += 3) {
        body(0, 2, kt);
        body(1, 0, kt + 1);
        body(2, 1, kt + 2);
    }
    body(0, 2, 30);
    body(1, 0, 31);

    // ---- epilogue: invl directly from osum (same row map as ot) ----
    int b = bh >> 4, h = bh & 15;
    unsigned short* ob = ((unsigned short*)KVs) + wave * 1152;   // 16 rows x 72
#pragma unroll
    for (int g = 0; g < 2; ++g) {
        float il[4];
#pragma unroll
        for (int r = 0; r < 4; ++r) il[r] = 1.0f / osum[g][r];
#pragma unroll
        for (int ht = 0; ht < 4; ++ht)
#pragma unroll
            for (int r = 0; r < 4; ++r)
                ob[(quad * 4 + r) * 72 + ht * 16 + l15] = f2bf(ot[g][ht][r] * il[r]);
        // wave-private region: ds_write -> ds_read ordered by lgkmcnt within wave
        int q_loc = lane >> 2, seg = lane & 3;
        unsigned short* dst = attn + ((long)(b * Nn + q0 + wave * 32 + g * 16 + q_loc)) * 1024 + h * 64 + seg * 16;
        *(short8*)dst       = *(const short8*)&ob[q_loc * 72 + seg * 16];
        *(short8*)(dst + 8) = *(const short8*)&ob[q_loc * 72 + seg * 16 + 8];
    }
}

// ---------------------------------------------------------------------------
// K5: out-projection v2 — gemm_qkv v3 structure (128x256, 2-phase, counted
// vmcnt). Grid 64x4 = 256 blocks = exactly 1 round at 1 block/CU.
// ---------------------------------------------------------------------------
__global__ __launch_bounds__(512, 1) void gemm_out(const unsigned short* __restrict__ A,
                                                   const unsigned short* __restrict__ Bt,
                                                   const float* __restrict__ bout,
                                                   float* __restrict__ out) {
    __shared__ unsigned short LDS[49152];   // 96 KiB: A[2][8192] @0, B[2][16384] @16384
    int r0 = blockIdx.x * 128, c0 = blockIdx.y * 256;
    int tid = threadIdx.x;
    int wv = tid >> 6, lane = tid & 63, l15 = lane & 15, quad = lane >> 4;
    int wm = wv >> 2, wn = wv & 3;          // 2M x 4N wave grid (64x64 each)

    floatx4 acc[4][4] = {};
    int swz0 = (quad ^ (l15 & 7)) << 3;
    int swz1 = ((4 | quad) ^ (l15 & 7)) << 3;

    auto stageA = [&](int tt) {
        unsigned short* base = &LDS[(tt & 1) * 8192];
        int k0 = tt * 64;
#pragma unroll
        for (int i = 0; i < 2; ++i) {
            int qq = (wv * 2 + i) * 64 + lane;
            int row = qq >> 3, cp = qq & 7;
            int sc = cp ^ (row & 7);
            load_lds16(&A[(r0 + row) * 1024 + k0 + sc * 8], &base[qq * 8]);
        }
    };
    auto stageB = [&](int tt) {
        unsigned short* base = &LDS[16384 + (tt & 1) * 16384];
        int k0 = tt * 64;
#pragma unroll
        for (int i = 0; i < 4; ++i) {
            int qq = (wv * 4 + i) * 64 + lane;
            int row = qq >> 3, cp = qq & 7;
            int sc = cp ^ (row & 7);
            load_lds16(&Bt[(c0 + row) * 1024 + k0 + sc * 8], &base[qq * 8]);
        }
    };

    stageA(0); stageB(0); stageA(1);
    asm volatile("s_waitcnt vmcnt(2)" ::: "memory");
    __builtin_amdgcn_s_barrier();

    for (int t = 0; t < 16; ++t) {
        int abuf = (t & 1) * 8192;
        int bbuf = 16384 + (t & 1) * 16384;
        short8 af[4][2], bf[2][2];

        // ---- phase 0 ----
        if (t < 15) stageB(t + 1);
#pragma unroll
        for (int mi = 0; mi < 4; ++mi) {
            af[mi][0] = *(const short8*)&LDS[abuf + (wm * 64 + mi * 16 + l15) * 64 + swz0];
            af[mi][1] = *(const short8*)&LDS[abuf + (wm * 64 + mi * 16 + l15) * 64 + swz1];
        }
#pragma unroll
        for (int ni = 0; ni < 2; ++ni) {
            bf[ni][0] = *(const short8*)&LDS[bbuf + (wn * 64 + ni * 16 + l15) * 64 + swz0];
            bf[ni][1] = *(const short8*)&LDS[bbuf + (wn * 64 + ni * 16 + l15) * 64 + swz1];
        }
        __builtin_amdgcn_s_barrier();
        asm volatile("s_waitcnt lgkmcnt(0)" ::: "memory");
        __builtin_amdgcn_s_setprio(1);
#pragma unroll
        for (int ks = 0; ks < 2; ++ks)
#pragma unroll
            for (int mi = 0; mi < 4; ++mi)
#pragma unroll
                for (int ni = 0; ni < 2; ++ni)
                    acc[mi][ni] = MFMA16(af[mi][ks], bf[ni][ks], acc[mi][ni]);
        __builtin_amdgcn_s_setprio(0);
        __builtin_amdgcn_s_barrier();

        // ---- phase 1 ----
        if (t < 14) stageA(t + 2);
#pragma unroll
        for (int ni = 0; ni < 2; ++ni) {
            bf[ni][0] = *(const short8*)&LDS[bbuf + (wn * 64 + 32 + ni * 16 + l15) * 64 + swz0];
            bf[ni][1] = *(const short8*)&LDS[bbuf + (wn * 64 + 32 + ni * 16 + l15) * 64 + swz1];
        }
        __builtin_amdgcn_s_barrier();
        asm volatile("s_waitcnt lgkmcnt(0)" ::: "memory");
        __builtin_amdgcn_s_setprio(1);
#pragma unroll
        for (int ks = 0; ks < 2; ++ks)
#pragma unroll
            for (int mi = 0; mi < 4; ++mi)
#pragma unroll
                for (int ni = 0; ni < 2; ++ni)
                    acc[mi][2 + ni] = MFMA16(af[mi][ks], bf[ni][ks], acc[mi][2 + ni]);
        __builtin_amdgcn_s_setprio(0);
        if (t < 14)       asm volatile("s_waitcnt vmcnt(2)" ::: "memory");
        else if (t == 14) asm volatile("s_waitcnt vmcnt(0)" ::: "memory");
        __builtin_amdgcn_s_barrier();
    }

#pragma unroll
    for (int ni = 0; ni < 4; ++ni) {
        int c = c0 + wn * 64 + ni * 16 + l15;
        float bias = bout[c];
#pragma unroll
        for (int mi = 0; mi < 4; ++mi)
#pragma unroll
            for (int r2 = 0; r2 < 4; ++r2) {
                int rr = r0 + wm * 64 + mi * 16 + quad * 4 + r2;
                out[rr * 1024 + c] = acc[mi][ni][r2] + bias;
            }
    }
}

// ---------------------------------------------------------------------------
extern "C" void kernel_launch(void* const* d_in, const int* in_sizes, int n_in,
                              void* d_out, int out_size, void* d_ws, size_t ws_size,
                              hipStream_t stream) {
    const float* x    = (const float*)d_in[0];
    const float* g    = (const float*)d_in[1];
    const float* be   = (const float*)d_in[2];
    const float* wqkv = (const float*)d_in[3];
    const float* wout = (const float*)d_in[4];
    const float* bout = (const float*)d_in[5];
    float* out = (float*)d_out;

    char* ws = (char*)d_ws;
    unsigned short* xn    = (unsigned short*)(ws);                 // 16 MB
    unsigned short* wqkvT = (unsigned short*)(ws + 16777216);      //  6 MB
    unsigned short* woutT = (unsigned short*)(ws + 23068672);      //  2 MB
    unsigned short* qb    = (unsigned short*)(ws + 25165824);      // 16 MB
    unsigned short* kb    = (unsigned short*)(ws + 41943040);      // 16 MB
    unsigned short* vt    = (unsigned short*)(ws + 58720256);      // 16 MB
    unsigned short* attn  = (unsigned short*)(ws + 75497472);      // 16 MB

    transpose_w<<<dim3(IN3 / 32, Dd / 32, 2), dim3(32, 8), 0, stream>>>(wqkv, wqkvT, wout, woutT);
    ln_kernel<<<RR, 256, 0, stream>>>(x, g, be, xn);
    gemm_qkv<<<dim3(RR / 128, IN3 / 256), 512, 0, stream>>>(xn, wqkvT, qb, kb, vt);
    attn_kernel<<<dim3(Nn / 128 * Bb * Hh), 256, 0, stream>>>(qb, kb, vt, attn);
    gemm_out<<<dim3(RR / 128, Dd / 256), 512, 0, stream>>>(attn, woutT, bout, out);
}

// Round 11
// 253.363 us; speedup vs baseline: 2.0878x; 1.0037x over previous
//
#include <hip/hip_runtime.h>
#include <hip/hip_bf16.h>

// Problem constants
#define Bb   4
#define Nn   2048
#define Dd   1024
#define Hh   16
#define HDd  64
#define IN3  3072          // 3 * H * HD
#define RR   8192          // B * N

// ---------------------------------------------------------------------------
// __launch_bounds__ EMPIRICAL MODEL (this compiler, gfx950) — R2/R5/R8 data:
//   VGPR cap = 512 / (2 * arg2) = 256 / arg2, INDEPENDENT of block size.
//   (512,1)->256  (512,2)->128  (256,2)->128  (256,3)->85  (256,4)->64
// Compiler allocates UP TO cap; exceeding it = scratch spill (WRITE_SIZE
// blow-up: 625MB R2, 1.05GB R8). Occupancy knobs on attn: <5% effect
// (R3/R9) — attn is pipe-sum bound; R11 targets the 3+1 dispatch tail.
// ---------------------------------------------------------------------------

typedef __attribute__((ext_vector_type(8))) short short8;
typedef __attribute__((ext_vector_type(4))) float floatx4;

#define MFMA16(a, b, c) __builtin_amdgcn_mfma_f32_16x16x32_bf16((a), (b), (c), 0, 0, 0)

static __device__ __forceinline__ unsigned short f2bf(float f) {
    union { float f; unsigned int u; } v; v.f = f;
    unsigned int r = v.u + 0x7fffu + ((v.u >> 16) & 1u);   // RNE
    return (unsigned short)(r >> 16);
}
static __device__ __forceinline__ float bf2f(unsigned short h) {
    union { unsigned int u; float f; } v; v.u = ((unsigned int)h) << 16;
    return v.f;
}

// raw v_exp_f32 (args small; no OCML fixup needed) [R6 win]
static __device__ __forceinline__ float fast_exp2(float x) {
#if __has_builtin(__builtin_amdgcn_exp2f)
    return __builtin_amdgcn_exp2f(x);
#else
    return exp2f(x);
#endif
}

// sin/cos via v_fract + v_sin/v_cos (revolutions) [R10 win, fused rope]
static __device__ __forceinline__ void sincos_rev(float ang, float& s, float& c) {
#if __has_builtin(__builtin_amdgcn_sinf) && __has_builtin(__builtin_amdgcn_cosf)
    float rev = ang * 0.15915494309189535f;
    rev = rev - floorf(rev);
    s = __builtin_amdgcn_sinf(rev);
    c = __builtin_amdgcn_cosf(rev);
#else
    s = sinf(ang);
    c = cosf(ang);
#endif
}

// async global->LDS DMA, 16B/lane (validated in-session R5-R10)
typedef const __attribute__((address_space(1))) void* gas1_t;
typedef __attribute__((address_space(3))) void* las3_t;
static __device__ __forceinline__ void load_lds16(const void* g, void* l) {
    __builtin_amdgcn_global_load_lds((gas1_t)(unsigned long long)g,
                                     (las3_t)(unsigned int)(unsigned long long)l,
                                     16, 0, 0);
}

// ---------------------------------------------------------------------------
// K0: transpose fp32 [rows][cols] -> bf16 [cols][rows], BOTH weights in one
// launch (grid.z: 0 = w_qkv 1024x3072, 1 = w_out 1024x1024). [R10 win]
// ---------------------------------------------------------------------------
__global__ void transpose_w(const float* __restrict__ s0, unsigned short* __restrict__ d0,
                            const float* __restrict__ s1, unsigned short* __restrict__ d1) {
    const float* src; unsigned short* dst; int cols;
    if (blockIdx.z == 0) { src = s0; dst = d0; cols = 3072; }
    else { if (blockIdx.x >= 32) return; src = s1; dst = d1; cols = 1024; }  // block-uniform
    __shared__ float tile[32][33];
    int c0 = blockIdx.x * 32, r0 = blockIdx.y * 32;
    int tx = threadIdx.x, ty = threadIdx.y;   // 32 x 8
#pragma unroll
    for (int i = 0; i < 4; ++i) tile[ty + 8 * i][tx] = src[(r0 + ty + 8 * i) * cols + c0 + tx];
    __syncthreads();
#pragma unroll
    for (int i = 0; i < 4; ++i) dst[(c0 + ty + 8 * i) * 1024 + r0 + tx] = f2bf(tile[tx][ty + 8 * i]);
}

// ---------------------------------------------------------------------------
// K1: LayerNorm fp32 -> bf16, one block (256 thr) per row of 1024
// ---------------------------------------------------------------------------
__global__ __launch_bounds__(256) void ln_kernel(const float* __restrict__ x,
                                                 const float* __restrict__ g,
                                                 const float* __restrict__ be,
                                                 unsigned short* __restrict__ xn) {
    int row = blockIdx.x, t = threadIdx.x;
    float4 v = ((const float4*)(x + row * Dd))[t];
    float s  = v.x + v.y + v.z + v.w;
    float sq = v.x * v.x + v.y * v.y + v.z * v.z + v.w * v.w;
#pragma unroll
    for (int off = 1; off < 64; off <<= 1) { s += __shfl_xor(s, off); sq += __shfl_xor(sq, off); }
    __shared__ float ps[4], pq2[4];
    int wv = t >> 6;
    if ((t & 63) == 0) { ps[wv] = s; pq2[wv] = sq; }
    __syncthreads();
    s  = ps[0] + ps[1] + ps[2] + ps[3];
    sq = pq2[0] + pq2[1] + pq2[2] + pq2[3];
    float mu   = s * (1.0f / Dd);
    float var  = sq * (1.0f / Dd) - mu * mu;
    float rstd = rsqrtf(var + 1e-5f);
    float4 gg = ((const float4*)g)[t];
    float4 bb = ((const float4*)be)[t];
    ushort4 o;
    o.x = f2bf((v.x - mu) * rstd * gg.x + bb.x);
    o.y = f2bf((v.y - mu) * rstd * gg.y + bb.y);
    o.z = f2bf((v.z - mu) * rstd * gg.z + bb.z);
    o.w = f2bf((v.w - mu) * rstd * gg.w + bb.w);
    ((ushort4*)(xn + row * Dd))[t] = o;
}

// ---------------------------------------------------------------------------
// K2: qkv GEMM v4 — 128x256 tile, 2-phase/K-tile counted-vmcnt schedule
// [R7-proven] + fused vtrans V-epilogue [R10-verified, absmax unchanged].
// ---------------------------------------------------------------------------
__global__ __launch_bounds__(512, 1) void gemm_qkv(const unsigned short* __restrict__ A,
                                                   const unsigned short* __restrict__ Bt,
                                                   unsigned short* __restrict__ qo,
                                                   unsigned short* __restrict__ ko,
                                                   unsigned short* __restrict__ vo) {
    __shared__ unsigned short LDS[49152];   // 96 KiB: A[2][8192] @0, B[2][16384] @16384
    int r0 = blockIdx.x * 128, c0 = blockIdx.y * 256;
    int tid = threadIdx.x;
    int wv = tid >> 6, lane = tid & 63, l15 = lane & 15, quad = lane >> 4;
    int wm = wv >> 2, wn = wv & 3;          // 2M x 4N wave grid (64x64 each)

    floatx4 acc[4][4] = {};
    int swz0 = (quad ^ (l15 & 7)) << 3;            // k-chunk quad   (ks=0)
    int swz1 = ((4 | quad) ^ (l15 & 7)) << 3;      // k-chunk 4+quad (ks=1)

    auto stageA = [&](int tt) {                    // 16 KB: 2 loads/lane
        unsigned short* base = &LDS[(tt & 1) * 8192];
        int k0 = tt * 64;
#pragma unroll
        for (int i = 0; i < 2; ++i) {
            int qq = (wv * 2 + i) * 64 + lane;     // 0..1023 (16B units)
            int row = qq >> 3, cp = qq & 7;
            int sc = cp ^ (row & 7);
            load_lds16(&A[(r0 + row) * 1024 + k0 + sc * 8], &base[qq * 8]);
        }
    };
    auto stageB = [&](int tt) {                    // 32 KB: 4 loads/lane
        unsigned short* base = &LDS[16384 + (tt & 1) * 16384];
        int k0 = tt * 64;
#pragma unroll
        for (int i = 0; i < 4; ++i) {
            int qq = (wv * 4 + i) * 64 + lane;     // 0..2047 (16B units)
            int row = qq >> 3, cp = qq & 7;
            int sc = cp ^ (row & 7);
            load_lds16(&Bt[(c0 + row) * 1024 + k0 + sc * 8], &base[qq * 8]);
        }
    };

    // prologue: A(0) 2 + B(0) 4 + A(1) 2 loads; vmcnt(2) -> tile0 landed
    stageA(0); stageB(0); stageA(1);
    asm volatile("s_waitcnt vmcnt(2)" ::: "memory");
    __builtin_amdgcn_s_barrier();

    for (int t = 0; t < 16; ++t) {
        int abuf = (t & 1) * 8192;
        int bbuf = 16384 + (t & 1) * 16384;
        short8 af[4][2], bf[2][2];

        // ---- phase 0: wave cols 0..31 (ni 0,1) ----
        if (t < 15) stageB(t + 1);
#pragma unroll
        for (int mi = 0; mi < 4; ++mi) {
            af[mi][0] = *(const short8*)&LDS[abuf + (wm * 64 + mi * 16 + l15) * 64 + swz0];
            af[mi][1] = *(const short8*)&LDS[abuf + (wm * 64 + mi * 16 + l15) * 64 + swz1];
        }
#pragma unroll
        for (int ni = 0; ni < 2; ++ni) {
            bf[ni][0] = *(const short8*)&LDS[bbuf + (wn * 64 + ni * 16 + l15) * 64 + swz0];
            bf[ni][1] = *(const short8*)&LDS[bbuf + (wn * 64 + ni * 16 + l15) * 64 + swz1];
        }
        __builtin_amdgcn_s_barrier();
        asm volatile("s_waitcnt lgkmcnt(0)" ::: "memory");
        __builtin_amdgcn_s_setprio(1);
#pragma unroll
        for (int ks = 0; ks < 2; ++ks)
#pragma unroll
            for (int mi = 0; mi < 4; ++mi)
#pragma unroll
                for (int ni = 0; ni < 2; ++ni)
                    acc[mi][ni] = MFMA16(af[mi][ks], bf[ni][ks], acc[mi][ni]);
        __builtin_amdgcn_s_setprio(0);
        __builtin_amdgcn_s_barrier();

        // ---- phase 1: wave cols 32..63 (ni 2,3); af held in regs ----
        if (t < 14) stageA(t + 2);   // lands in CURRENT A-buf; A-reads done at ph0 barrier
#pragma unroll
        for (int ni = 0; ni < 2; ++ni) {
            bf[ni][0] = *(const short8*)&LDS[bbuf + (wn * 64 + 32 + ni * 16 + l15) * 64 + swz0];
            bf[ni][1] = *(const short8*)&LDS[bbuf + (wn * 64 + 32 + ni * 16 + l15) * 64 + swz1];
        }
        __builtin_amdgcn_s_barrier();
        asm volatile("s_waitcnt lgkmcnt(0)" ::: "memory");
        __builtin_amdgcn_s_setprio(1);
#pragma unroll
        for (int ks = 0; ks < 2; ++ks)
#pragma unroll
            for (int mi = 0; mi < 4; ++mi)
#pragma unroll
                for (int ni = 0; ni < 2; ++ni)
                    acc[mi][2 + ni] = MFMA16(af[mi][ks], bf[ni][ks], acc[mi][2 + ni]);
        __builtin_amdgcn_s_setprio(0);
        // counted vmcnt: retire A(t+1)+B(t+1) (needed by body t+1); leave
        // A(t+2) (2 loads) in flight across the barrier (T4).
        if (t < 14)       asm volatile("s_waitcnt vmcnt(2)" ::: "memory");
        else if (t == 14) asm volatile("s_waitcnt vmcnt(0)" ::: "memory");   // drain tail
        __builtin_amdgcn_s_barrier();
    }

    if (c0 >= 2048) {
        // ---- fused V epilogue: transpose + kperm through LDS -> vt ----
        unsigned short* T2 = LDS;
#pragma unroll
        for (int mi = 0; mi < 4; ++mi)
#pragma unroll
            for (int ni = 0; ni < 4; ++ni) {
                ushort4 w4;
                w4.x = f2bf(acc[mi][ni][0]);
                w4.y = f2bf(acc[mi][ni][1]);
                w4.z = f2bf(acc[mi][ni][2]);
                w4.w = f2bf(acc[mi][ni][3]);
                int col = wn * 64 + ni * 16 + l15;             // v-col (0..255)
                int row = wm * 64 + mi * 16 + quad * 4;        // local n (0..124, mult of 4)
                *(ushort4*)&T2[col * 136 + row] = w4;
            }
        __syncthreads();
        // gather permuted 4-row runs; each thread owns (col, 64-n segment)
        int col = tid >> 1, seg = tid & 1;
        int hglob = ((c0 - 2048) >> 6) + (col >> 6);           // head 0..15
        int j = col & 63;
        int b = r0 >> 11;
        int n0g = (r0 & 2047) + seg * 64;
        unsigned short tmp[64];
#pragma unroll
        for (int gi = 0; gi < 16; ++gi) {
            int blk = seg * 2 + (gi >> 3);
            int srow = blk * 32 + 16 * (gi & 1) + 4 * ((gi >> 1) & 3);
            *(ushort4*)&tmp[gi * 4] = *(const ushort4*)&T2[col * 136 + srow];
        }
        unsigned short* dst = vo + (((long)(b * 16 + hglob)) * 64 + j) * 2048 + n0g;
#pragma unroll
        for (int k2 = 0; k2 < 8; ++k2)
            *(short8*)(dst + k2 * 8) = *(const short8*)&tmp[k2 * 8];
        return;
    }

    // ---- fused RoPE for q,k blocks (block-uniform branch; c0 < 2048) ----
    {
        const float crope = 13.287712379549449f / 32.0f;   // log2(10000)/32
        float invf0 = fast_exp2(-(float)l15 * crope);          // j = l15
        float invf1 = fast_exp2(-(float)(l15 + 16) * crope);   // j = 16+l15
#pragma unroll
        for (int mi = 0; mi < 4; ++mi)
#pragma unroll
            for (int r2 = 0; r2 < 4; ++r2) {
                int rr = r0 + wm * 64 + mi * 16 + quad * 4 + r2;
                float n = (float)(rr & 2047);
                float s0, c0r, s1, c1r;
                sincos_rev(n * invf0, s0, c0r);
                sincos_rev(n * invf1, s1, c1r);
                float t1a = acc[mi][0][r2], t2a = acc[mi][2][r2];
                acc[mi][0][r2] = t1a * c0r - t2a * s0;
                acc[mi][2][r2] = t2a * c0r + t1a * s0;
                float t1b = acc[mi][1][r2], t2b = acc[mi][3][r2];
                acc[mi][1][r2] = t1b * c1r - t2b * s1;
                acc[mi][3][r2] = t2b * c1r + t1b * s1;
            }
    }
    // q pre-scale: fold softmax scale*log2(e) into q so attn does raw exp2
    if (c0 < 1024) {
        const float qsc = 0.125f * 1.4426950408889634f;
#pragma unroll
        for (int mi = 0; mi < 4; ++mi)
#pragma unroll
            for (int ni = 0; ni < 4; ++ni)
#pragma unroll
                for (int r2 = 0; r2 < 4; ++r2) acc[mi][ni][r2] *= qsc;
    }
    // epilogue: C/D layout col = lane&15, row = quad*4 + reg (verified m89/m91)
    unsigned short* outp = (c0 < 1024) ? qo : ko;   // block-uniform
#pragma unroll
    for (int ni = 0; ni < 4; ++ni) {
        int c = c0 + wn * 64 + ni * 16 + l15;
        int cin = c & 1023;
        int h = cin >> 6, j = cin & 63;
#pragma unroll
        for (int mi = 0; mi < 4; ++mi) {
#pragma unroll
            for (int r2 = 0; r2 < 4; ++r2) {
                int rr = r0 + wm * 64 + mi * 16 + quad * 4 + r2;
                int b = rr >> 11, n = rr & 2047;
                int bh = b * 16 + h;
                outp[(bh * 2048 + n) * 64 + j] = f2bf(acc[mi][ni][r2]);
            }
        }
    }
}

// ---------------------------------------------------------------------------
// K4: flash attention v15 — tail-free packing via block SHAPE (not schedule).
// R10: attn 73.2us, Occupancy 23%: LDS 48K -> 3 blocks/CU but grid 1024 =
// 4 blocks/CU of work -> 3-full + 1-sparse rounds per CU. R9 proved LDS
// shrink (2-deep) costs more than the tail; R7 proved the 3-deep counted
// body is best. v15: QBLK 256, 8 waves/block (512 thr), SAME per-wave body
// (32 q-rows, 2 groups, 84 VGPR). Grid 512 = EXACTLY 2 blocks/CU, zero
// tail; 16 waves/CU (4/SIMD). LDS 2x48K = 96K <= 160K. Staging splits over
// 8 waves: 1 K + 1 V load/lane -> vmcnt(2)/body. launch_bounds(512,2) ->
// cap 128 (model) >= 84 live.
// ---------------------------------------------------------------------------
__global__ __launch_bounds__(512, 2) void attn_kernel(const unsigned short* __restrict__ q,
                                                      const unsigned short* __restrict__ k,
                                                      const unsigned short* __restrict__ vt,
                                                      unsigned short* __restrict__ attn) {
    __shared__ unsigned short KVs[3][2][64 * 64];  // [buf][K/V][row*64+swizzled] 48 KiB
    // XCD-affine decode: fid%8 = XCD; qi fastest within XCD -> K/V L2-resident.
    int fid = blockIdx.x;
    int xcd = fid & 7, rest = fid >> 3;
    int qi = rest & 7, bhg = rest >> 3;            // qi 0..7, bhg 0..7
    int bh = bhg * 8 + xcd;
    int q0 = qi * 256;
    int tid = threadIdx.x;
    int wave = tid >> 6, lane = tid & 63, l15 = lane & 15, quad = lane >> 4;
    const unsigned short* qb  = q  + bh * (Nn * HDd);
    const unsigned short* kbp = k  + bh * (Nn * HDd);
    const unsigned short* vb  = vt + bh * (HDd * Nn);   // [hd][n], key-permuted
    int qbase = q0 + wave * 32;

    // Q fragments (B-operand of 16x16x32), 2 groups of 16 q-rows per wave
    short8 bq[2][2];
#pragma unroll
    for (int g = 0; g < 2; ++g) {
        bq[g][0] = *(const short8*)&qb[(qbase + g * 16 + l15) * 64 + quad * 8];
        bq[g][1] = *(const short8*)&qb[(qbase + g * 16 + l15) * 64 + 32 + quad * 8];
    }

    // 8 waves stage 16 KB (K 8 KB + V 8 KB): 1 K + 1 V load per lane
    auto stage = [&](int buf, int kb0) {
        int p = wave * 64 + lane;                      // 0..511 (16B units)
        int row = p >> 3, pr = p & 7;
        int sc = pr ^ (row & 7);                       // XOR chunk swizzle
        load_lds16(&kbp[(kb0 + row) * 64 + sc * 8], &KVs[buf][0][p * 8]);
        load_lds16(&vb[row * Nn + kb0 + sc * 8],    &KVs[buf][1][p * 8]);
    };

    floatx4 ot[2][4] = {};                 // [g][ht]: O[q=quad*4+r][hd=ht*16+l15]
    floatx4 osum[2] = {};                  // row-sum of P via ones-MFMA; same row map
    const floatx4 fz = {0.0f, 0.0f, 0.0f, 0.0f};
    const short8 vones = {(short)0x3F80, (short)0x3F80, (short)0x3F80, (short)0x3F80,
                          (short)0x3F80, (short)0x3F80, (short)0x3F80, (short)0x3F80};
    int swz0 = (quad ^ (l15 & 7)) << 3;                    // chunk quad   (c=0)
    int swz1 = ((4 | quad) ^ (l15 & 7)) << 3;              // chunk 4+quad (c=1)

    // body(cur, nxt, kt): compute tile kt from KVs[cur]; stage kt+2 into
    // KVs[nxt] (= buffer read at kt-1: all waves past that read via barrier).
    auto body = [&](int cur, int nxt, int kt) {
        if (kt + 2 < 32) stage(nxt, (kt + 2) * 64);
        const unsigned short* Kc = KVs[cur][0];
        const unsigned short* Vc = KVs[cur][1];
        // ---- S^T = K.Q^T ----
        short8 ka0[4], ka1[4];
#pragma unroll
        for (int mb = 0; mb < 4; ++mb) {
            ka0[mb] = *(const short8*)&Kc[(mb * 16 + l15) * 64 + swz0];
            ka1[mb] = *(const short8*)&Kc[(mb * 16 + l15) * 64 + swz1];
        }
        short8 bv0[4], bv1[4];
#pragma unroll
        for (int ht = 0; ht < 4; ++ht) {
            int row = (ht * 16 + l15) * 64;
            bv0[ht] = *(const short8*)&Vc[row + swz0];
            bv1[ht] = *(const short8*)&Vc[row + swz1];
        }
#pragma unroll
        for (int g = 0; g < 2; ++g) {
            floatx4 st[4];
            __builtin_amdgcn_s_setprio(1);
#pragma unroll
            for (int mb = 0; mb < 4; ++mb) {
                floatx4 z = MFMA16(ka0[mb], bq[g][0], fz);
                st[mb] = MFMA16(ka1[mb], bq[g][1], z);
            }
            __builtin_amdgcn_s_setprio(0);
            // ---- P = exp2(S) (q pre-scaled); pack K=32 A-fragments ----
            short8 pa[2];
#pragma unroll
            for (int c = 0; c < 2; ++c) {
                union { ushort4 u[2]; short8 s; } w;
#pragma unroll
                for (int t2 = 0; t2 < 2; ++t2) {
                    int mb = 2 * c + t2;
                    float p0 = fast_exp2(st[mb][0]);
                    float p1 = fast_exp2(st[mb][1]);
                    float p2 = fast_exp2(st[mb][2]);
                    float p3 = fast_exp2(st[mb][3]);
                    *(__hip_bfloat162*)&w.u[t2].x = __float22bfloat162_rn(float2{p0, p1});
                    *(__hip_bfloat162*)&w.u[t2].z = __float22bfloat162_rn(float2{p2, p3});
                }
                pa[c] = w.s;
            }
            // ---- O[q][hd] += P.V ; denom += P.1  (all in matrix pipe) ----
            __builtin_amdgcn_s_setprio(1);
            osum[g] = MFMA16(pa[0], vones, osum[g]);
            osum[g] = MFMA16(pa[1], vones, osum[g]);
#pragma unroll
            for (int ht = 0; ht < 4; ++ht) {
                ot[g][ht] = MFMA16(pa[0], bv0[ht], ot[g][ht]);
                ot[g][ht] = MFMA16(pa[1], bv1[ht], ot[g][ht]);
            }
            __builtin_amdgcn_s_setprio(0);
        }
        // counted vmcnt: this wave's 2 loads for kt+2 may stay in flight past
        // the barrier; kt+1's 2 loads are retired. Raw barrier (T4).
        if (kt < 30)       asm volatile("s_waitcnt vmcnt(2)" ::: "memory");
        else if (kt == 30) asm volatile("s_waitcnt vmcnt(0)" ::: "memory");
        __builtin_amdgcn_s_barrier();
    };

    stage(0, 0);
    stage(1, 64);
    asm volatile("s_waitcnt vmcnt(2)" ::: "memory");   // tile 0 landed
    __builtin_amdgcn_s_barrier();
    for (int kt = 0; kt < 30; kt += 3) {
        body(0, 2, kt);
        body(1, 0, kt + 1);
        body(2, 1, kt + 2);
    }
    body(0, 2, 30);
    body(1, 0, 31);

    // ---- epilogue: invl directly from osum (same row map as ot) ----
    int b = bh >> 4, h = bh & 15;
    unsigned short* ob = ((unsigned short*)KVs) + wave * 1152;   // 16 rows x 72; 8w = 18KB
#pragma unroll
    for (int g = 0; g < 2; ++g) {
        float il[4];
#pragma unroll
        for (int r = 0; r < 4; ++r) il[r] = 1.0f / osum[g][r];
#pragma unroll
        for (int ht = 0; ht < 4; ++ht)
#pragma unroll
            for (int r = 0; r < 4; ++r)
                ob[(quad * 4 + r) * 72 + ht * 16 + l15] = f2bf(ot[g][ht][r] * il[r]);
        // wave-private region: ds_write -> ds_read ordered by lgkmcnt within wave
        int q_loc = lane >> 2, seg = lane & 3;
        unsigned short* dst = attn + ((long)(b * Nn + q0 + wave * 32 + g * 16 + q_loc)) * 1024 + h * 64 + seg * 16;
        *(short8*)dst       = *(const short8*)&ob[q_loc * 72 + seg * 16];
        *(short8*)(dst + 8) = *(const short8*)&ob[q_loc * 72 + seg * 16 + 8];
    }
}

// ---------------------------------------------------------------------------
// K5: out-projection v2 — gemm_qkv v3 structure (128x256, 2-phase, counted
// vmcnt). Grid 64x4 = 256 blocks = exactly 1 round at 1 block/CU.
// ---------------------------------------------------------------------------
__global__ __launch_bounds__(512, 1) void gemm_out(const unsigned short* __restrict__ A,
                                                   const unsigned short* __restrict__ Bt,
                                                   const float* __restrict__ bout,
                                                   float* __restrict__ out) {
    __shared__ unsigned short LDS[49152];   // 96 KiB: A[2][8192] @0, B[2][16384] @16384
    int r0 = blockIdx.x * 128, c0 = blockIdx.y * 256;
    int tid = threadIdx.x;
    int wv = tid >> 6, lane = tid & 63, l15 = lane & 15, quad = lane >> 4;
    int wm = wv >> 2, wn = wv & 3;          // 2M x 4N wave grid (64x64 each)

    floatx4 acc[4][4] = {};
    int swz0 = (quad ^ (l15 & 7)) << 3;
    int swz1 = ((4 | quad) ^ (l15 & 7)) << 3;

    auto stageA = [&](int tt) {
        unsigned short* base = &LDS[(tt & 1) * 8192];
        int k0 = tt * 64;
#pragma unroll
        for (int i = 0; i < 2; ++i) {
            int qq = (wv * 2 + i) * 64 + lane;
            int row = qq >> 3, cp = qq & 7;
            int sc = cp ^ (row & 7);
            load_lds16(&A[(r0 + row) * 1024 + k0 + sc * 8], &base[qq * 8]);
        }
    };
    auto stageB = [&](int tt) {
        unsigned short* base = &LDS[16384 + (tt & 1) * 16384];
        int k0 = tt * 64;
#pragma unroll
        for (int i = 0; i < 4; ++i) {
            int qq = (wv * 4 + i) * 64 + lane;
            int row = qq >> 3, cp = qq & 7;
            int sc = cp ^ (row & 7);
            load_lds16(&Bt[(c0 + row) * 1024 + k0 + sc * 8], &base[qq * 8]);
        }
    };

    stageA(0); stageB(0); stageA(1);
    asm volatile("s_waitcnt vmcnt(2)" ::: "memory");
    __builtin_amdgcn_s_barrier();

    for (int t = 0; t < 16; ++t) {
        int abuf = (t & 1) * 8192;
        int bbuf = 16384 + (t & 1) * 16384;
        short8 af[4][2], bf[2][2];

        // ---- phase 0 ----
        if (t < 15) stageB(t + 1);
#pragma unroll
        for (int mi = 0; mi < 4; ++mi) {
            af[mi][0] = *(const short8*)&LDS[abuf + (wm * 64 + mi * 16 + l15) * 64 + swz0];
            af[mi][1] = *(const short8*)&LDS[abuf + (wm * 64 + mi * 16 + l15) * 64 + swz1];
        }
#pragma unroll
        for (int ni = 0; ni < 2; ++ni) {
            bf[ni][0] = *(const short8*)&LDS[bbuf + (wn * 64 + ni * 16 + l15) * 64 + swz0];
            bf[ni][1] = *(const short8*)&LDS[bbuf + (wn * 64 + ni * 16 + l15) * 64 + swz1];
        }
        __builtin_amdgcn_s_barrier();
        asm volatile("s_waitcnt lgkmcnt(0)" ::: "memory");
        __builtin_amdgcn_s_setprio(1);
#pragma unroll
        for (int ks = 0; ks < 2; ++ks)
#pragma unroll
            for (int mi = 0; mi < 4; ++mi)
#pragma unroll
                for (int ni = 0; ni < 2; ++ni)
                    acc[mi][ni] = MFMA16(af[mi][ks], bf[ni][ks], acc[mi][ni]);
        __builtin_amdgcn_s_setprio(0);
        __builtin_amdgcn_s_barrier();

        // ---- phase 1 ----
        if (t < 14) stageA(t + 2);
#pragma unroll
        for (int ni = 0; ni < 2; ++ni) {
            bf[ni][0] = *(const short8*)&LDS[bbuf + (wn * 64 + 32 + ni * 16 + l15) * 64 + swz0];
            bf[ni][1] = *(const short8*)&LDS[bbuf + (wn * 64 + 32 + ni * 16 + l15) * 64 + swz1];
        }
        __builtin_amdgcn_s_barrier();
        asm volatile("s_waitcnt lgkmcnt(0)" ::: "memory");
        __builtin_amdgcn_s_setprio(1);
#pragma unroll
        for (int ks = 0; ks < 2; ++ks)
#pragma unroll
            for (int mi = 0; mi < 4; ++mi)
#pragma unroll
                for (int ni = 0; ni < 2; ++ni)
                    acc[mi][2 + ni] = MFMA16(af[mi][ks], bf[ni][ks], acc[mi][2 + ni]);
        __builtin_amdgcn_s_setprio(0);
        if (t < 14)       asm volatile("s_waitcnt vmcnt(2)" ::: "memory");
        else if (t == 14) asm volatile("s_waitcnt vmcnt(0)" ::: "memory");
        __builtin_amdgcn_s_barrier();
    }

#pragma unroll
    for (int ni = 0; ni < 4; ++ni) {
        int c = c0 + wn * 64 + ni * 16 + l15;
        float bias = bout[c];
#pragma unroll
        for (int mi = 0; mi < 4; ++mi)
#pragma unroll
            for (int r2 = 0; r2 < 4; ++r2) {
                int rr = r0 + wm * 64 + mi * 16 + quad * 4 + r2;
                out[rr * 1024 + c] = acc[mi][ni][r2] + bias;
            }
    }
}

// ---------------------------------------------------------------------------
extern "C" void kernel_launch(void* const* d_in, const int* in_sizes, int n_in,
                              void* d_out, int out_size, void* d_ws, size_t ws_size,
                              hipStream_t stream) {
    const float* x    = (const float*)d_in[0];
    const float* g    = (const float*)d_in[1];
    const float* be   = (const float*)d_in[2];
    const float* wqkv = (const float*)d_in[3];
    const float* wout = (const float*)d_in[4];
    const float* bout = (const float*)d_in[5];
    float* out = (float*)d_out;

    char* ws = (char*)d_ws;
    unsigned short* xn    = (unsigned short*)(ws);                 // 16 MB
    unsigned short* wqkvT = (unsigned short*)(ws + 16777216);      //  6 MB
    unsigned short* woutT = (unsigned short*)(ws + 23068672);      //  2 MB
    unsigned short* qb    = (unsigned short*)(ws + 25165824);      // 16 MB
    unsigned short* kb    = (unsigned short*)(ws + 41943040);      // 16 MB
    unsigned short* vt    = (unsigned short*)(ws + 58720256);      // 16 MB
    unsigned short* attn  = (unsigned short*)(ws + 75497472);      // 16 MB

    transpose_w<<<dim3(IN3 / 32, Dd / 32, 2), dim3(32, 8), 0, stream>>>(wqkv, wqkvT, wout, woutT);
    ln_kernel<<<RR, 256, 0, stream>>>(x, g, be, xn);
    gemm_qkv<<<dim3(RR / 128, IN3 / 256), 512, 0, stream>>>(xn, wqkvT, qb, kb, vt);
    attn_kernel<<<dim3(Nn / 256 * Bb * Hh), 512, 0, stream>>>(qb, kb, vt, attn);
    gemm_out<<<dim3(RR / 128, Dd / 256), 512, 0, stream>>>(attn, woutT, bout, out);
}